// Round 4
// baseline (788.636 us; speedup 1.0000x reference)
//
#include <hip/hip_runtime.h>
#include <math.h>

#define INV_SQRT2 0.70710678118654752f
#define INV_SQRT32 0.17677669529663689f

// One thread per batch element. All small weights staged/precomputed in LDS.
__device__ __forceinline__ void nearest_d8(const float* xx, float* y) {
  float f[8], err[8];
#pragma unroll
  for (int d = 0; d < 8; ++d) { f[d] = rintf(xx[d]); err[d] = xx[d] - f[d]; }
  int idx = 0; float best = -1.0f;
#pragma unroll
  for (int d = 0; d < 8; ++d) { float a = fabsf(err[d]); if (a > best) { best = a; idx = d; } }
  float fs = 0.f;
#pragma unroll
  for (int d = 0; d < 8; ++d) fs += f[d];
  bool ok = ((((int)fs) & 1) == 0);   // mod(f.sum,2)==0  (exact small ints)
#pragma unroll
  for (int d = 0; d < 8; ++d) {
    float g = f[d] + ((d == idx) ? ((err[d] >= 0.f) ? 1.f : -1.f) : 0.f);
    y[d] = ok ? f[d] : g;
  }
}

// waves_per_eu(4,4): pin allocator to a 128-VGPR budget (512/4). Rounds 2-3
// showed that a min-only hint makes the backend target 2x the min and spill.
extern "C" __global__ void __launch_bounds__(256)
__attribute__((amdgpu_waves_per_eu(4, 4)))
e8_kernel(const float* __restrict__ colony, const float* __restrict__ conf,
          const float* __restrict__ Wq, const float* __restrict__ bq,
          const float* __restrict__ Wk, const float* __restrict__ bk,
          const float* __restrict__ Wv, const float* __restrict__ bv,
          const float* __restrict__ comm, const float* __restrict__ role,
          const float* __restrict__ mha_w, const float* __restrict__ mha_b,
          const float* __restrict__ W1, const float* __restrict__ b1,
          const float* __restrict__ W2, const float* __restrict__ b2,
          const float* __restrict__ gate, float* __restrict__ out, int B)
{
  __shared__ float sM8[64], sU[8], sV[8], sCc[1];
  __shared__ float sComm[49], sRole[7];
  __shared__ float sWq3[64], sWk3[64], sBq3[8], sBk3[8];
  __shared__ float sWv[64], sBv[8];
  __shared__ float sW1[256], sB1[32], sW2[256], sB2[8];
  __shared__ float sGate[1];

  const int t = threadIdx.x;
  if (t < 64) {
    int i = t >> 3, j = t & 7;
    float a = 0.f;
    for (int h = 0; h < 32; ++h) a += Wq[h * 8 + i] * Wk[h * 8 + j];
    sM8[t] = a;
    sWq3[t] = mha_w[t];
    sWk3[t] = mha_w[64 + t];
    sWv[t] = Wv[t];
  } else if (t < 72) {
    int j = t - 64;
    float a = 0.f, bb = 0.f;
    for (int h = 0; h < 32; ++h) { a += bq[h] * Wk[h * 8 + j]; bb += bk[h] * Wq[h * 8 + j]; }
    sU[j] = a; sV[j] = bb;
    sBq3[j] = mha_b[j]; sBk3[j] = mha_b[8 + j]; sBv[j] = bv[j]; sB2[j] = b2[j];
  } else if (t == 72) {
    float c = 0.f;
    for (int h = 0; h < 32; ++h) c += bq[h] * bk[h];
    sCc[0] = c;
    sGate[0] = 1.f / (1.f + expf(-gate[0]));
  } else if (t >= 80 && t < 87) {
    int n = t - 80;
    float mx = -1e30f;
    for (int m = 0; m < 7; ++m) mx = fmaxf(mx, comm[n * 7 + m]);
    float e[7], s = 0.f;
    for (int m = 0; m < 7; ++m) { e[m] = expf(comm[n * 7 + m] - mx); s += e[m]; }
    for (int m = 0; m < 7; ++m) sComm[n * 7 + m] = e[m] / s;
  } else if (t == 87) {
    float mx = -1e30f;
    for (int m = 0; m < 7; ++m) mx = fmaxf(mx, role[m]);
    float e[7], s = 0.f;
    for (int m = 0; m < 7; ++m) { e[m] = expf(role[m] - mx); s += e[m]; }
    for (int m = 0; m < 7; ++m) sRole[m] = e[m] / s;
  }
  sW1[t] = W1[t];
  sW2[t] = W2[t];
  if (t < 32) sB1[t] = b1[t];
  __syncthreads();

  const int b = blockIdx.x * 256 + t;
  if (b >= B) return;

  // ---- load + normalize x (7 rows of 8) ----
  const float* px = colony + (size_t)b * 56;
  float x[7][8];
#pragma unroll
  for (int n = 0; n < 7; ++n) {
    float4 v0 = *(const float4*)(px + n * 8);
    float4 v1 = *(const float4*)(px + n * 8 + 4);
    x[n][0] = v0.x; x[n][1] = v0.y; x[n][2] = v0.z; x[n][3] = v0.w;
    x[n][4] = v1.x; x[n][5] = v1.y; x[n][6] = v1.z; x[n][7] = v1.w;
    float ss = 0.f;
#pragma unroll
    for (int d = 0; d < 8; ++d) ss += x[n][d] * x[n][d];
    float inv = 1.0f / fmaxf(sqrtf(ss), 1e-12f);
#pragma unroll
    for (int d = 0; d < 8; ++d) x[n][d] = x[n][d] * inv;
  }

  // ---- mean over n ----
  float xm[8];
#pragma unroll
  for (int d = 0; d < 8; ++d) {
    float s = 0.f;
#pragma unroll
    for (int n = 0; n < 7; ++n) s += x[n][d];
    xm[d] = s * (1.0f / 7.0f);
  }

  // ---- scores via collapsed q·k ----
  float w8[8];
#pragma unroll
  for (int j = 0; j < 8; ++j) {
    float a = 0.f;
#pragma unroll
    for (int i = 0; i < 8; ++i) a += xm[i] * sM8[i * 8 + j];
    w8[j] = a + sU[j];
  }
  float base = sCc[0];
#pragma unroll
  for (int i = 0; i < 8; ++i) base += sV[i] * xm[i];
  float sc[7];
#pragma unroll
  for (int n = 0; n < 7; ++n) {
    float a = base;
#pragma unroll
    for (int j = 0; j < 8; ++j) a += w8[j] * x[n][j];
    sc[n] = a * INV_SQRT32;
  }
  float sc2[7];
#pragma unroll
  for (int m = 0; m < 7; ++m) {
    float a = 0.f;
#pragma unroll
    for (int n = 0; n < 7; ++n) a += sc[n] * sComm[n * 7 + m];
    sc2[m] = a + sRole[m];
  }

  // ---- tiny 4-head MHA; K staged per head, Q computed on the fly ----
  float mhs[7];
#pragma unroll
  for (int m = 0; m < 7; ++m) mhs[m] = 0.f;
#pragma unroll
  for (int h = 0; h < 4; ++h) {
    float Kh[7][2];
#pragma unroll
    for (int m = 0; m < 7; ++m) {
#pragma unroll
      for (int r2 = 0; r2 < 2; ++r2) {
        int rr = 2 * h + r2;
        float ak = sBk3[rr];
#pragma unroll
        for (int j = 0; j < 8; ++j) ak += x[m][j] * sWk3[rr * 8 + j];
        Kh[m][r2] = ak;
      }
    }
#pragma unroll
    for (int n = 0; n < 7; ++n) {
      float q0 = sBq3[2 * h], q1 = sBq3[2 * h + 1];
#pragma unroll
      for (int j = 0; j < 8; ++j) {
        q0 += x[n][j] * sWq3[(2 * h) * 8 + j];
        q1 += x[n][j] * sWq3[(2 * h + 1) * 8 + j];
      }
      float e[7], mx = -1e30f;
#pragma unroll
      for (int m = 0; m < 7; ++m) {
        float a = q0 * Kh[m][0] + q1 * Kh[m][1];
        e[m] = a * INV_SQRT2;
        mx = fmaxf(mx, e[m]);
      }
      float s = 0.f;
#pragma unroll
      for (int m = 0; m < 7; ++m) { e[m] = __expf(e[m] - mx); s += e[m]; }
      float inv = 1.0f / s;
#pragma unroll
      for (int m = 0; m < 7; ++m) mhs[m] += e[m] * inv;
    }
  }

  // ---- combine scores, softmax, confidence re-norm ----
  float scf[7], mx = -1e30f;
#pragma unroll
  for (int m = 0; m < 7; ++m) {
    scf[m] = 0.7f * sc2[m] + 0.3f * ((mhs[m] * 0.25f) * (1.0f / 7.0f));
    mx = fmaxf(mx, scf[m]);
  }
  float e[7], s = 0.f;
#pragma unroll
  for (int m = 0; m < 7; ++m) { e[m] = __expf(scf[m] - mx); s += e[m]; }
  float sinv = 1.0f / s;
  float w[7], ws = 0.f;
  const float* pc = conf + (size_t)b * 7;
#pragma unroll
  for (int m = 0; m < 7; ++m) { w[m] = (e[m] * sinv) * pc[m]; ws += w[m]; }
  float dinv = 1.0f / fmaxf(ws, 1e-8f);
#pragma unroll
  for (int m = 0; m < 7; ++m) w[m] = w[m] * dinv;

  // ---- combined = Wv (Σ w_n x_n) + bv ----
  float xc[8];
#pragma unroll
  for (int d = 0; d < 8; ++d) {
    float a = 0.f;
#pragma unroll
    for (int n = 0; n < 7; ++n) a += w[n] * x[n][d];
    xc[d] = a;
  }
  float comb[8];
#pragma unroll
  for (int i = 0; i < 8; ++i) {
    float a = sBv[i];
#pragma unroll
    for (int j = 0; j < 8; ++j) a += sWv[i * 8 + j] * xc[j];
    comb[i] = a;
  }

  // ---- MLP: gelu(exact) ----
  float o8[8];
#pragma unroll
  for (int i = 0; i < 8; ++i) o8[i] = sB2[i];
#pragma unroll
  for (int i = 0; i < 32; ++i) {
    float a = sB1[i];
#pragma unroll
    for (int j = 0; j < 8; ++j) a += sW1[i * 8 + j] * comb[j];
    float g = 0.5f * a * (1.f + erff(a * INV_SQRT2));
#pragma unroll
    for (int k = 0; k < 8; ++k) o8[k] += sW2[k * 32 + i] * g;
  }

  // ---- refined = norm(combined + sigmoid(gate)*h) ----
  float gsig = sGate[0];
  float pre[8], ss2 = 0.f;
#pragma unroll
  for (int d = 0; d < 8; ++d) { pre[d] = comb[d] + gsig * o8[d]; ss2 += pre[d] * pre[d]; }
  float ninv = 1.0f / fmaxf(sqrtf(ss2), 1e-12f);
  float r[8];
#pragma unroll
  for (int d = 0; d < 8; ++d) r[d] = pre[d] * ninv;

  // ---- nearest E8 point (quantized == hard) ----
  float y0[8], y1[8], xs[8];
  nearest_d8(r, y0);
#pragma unroll
  for (int d = 0; d < 8; ++d) xs[d] = r[d] - 0.5f;
  nearest_d8(xs, y1);
#pragma unroll
  for (int d = 0; d < 8; ++d) y1[d] += 0.5f;
  float d0 = 0.f, d1 = 0.f;
#pragma unroll
  for (int d = 0; d < 8; ++d) {
    float a = r[d] - y0[d], bb = r[d] - y1[d];
    d0 += a * a; d1 += bb * bb;
  }
  bool use0 = (d0 <= d1);

  // ---- store quantized + weights NOW (kills y0/y1/hard before argmin tables) ----
  float* outq = out;
  float* outi = out + (size_t)B * 8;
  float* outw = out + (size_t)B * 9;
  {
    float q0v[8];
#pragma unroll
    for (int d = 0; d < 8; ++d) {
      float hd = use0 ? y0[d] : y1[d];
      q0v[d] = r[d] + (hd - r[d]);
    }
    *(float4*)(outq + (size_t)b * 8)     = make_float4(q0v[0], q0v[1], q0v[2], q0v[3]);
    *(float4*)(outq + (size_t)b * 8 + 4) = make_float4(q0v[4], q0v[5], q0v[6], q0v[7]);
  }
#pragma unroll
  for (int m = 0; m < 7; ++m) outw[(size_t)b * 7 + m] = w[m];

  // ---- argmin over 240 E8 roots ----
  // sq = fmaf(-2,dot,ssum) + 2: identical rounding to (ssum - 2*dot) + 2
  // since 2*dot is exact. First strict minimum wins (matches jnp.argmin).
  float ssum = 0.f;
#pragma unroll
  for (int d = 0; d < 8; ++d) ssum += r[d] * r[d];
  float bestSq = 1e30f, bestIdxF = 0.f;
  int idx = 0;
#pragma unroll
  for (int i = 0; i < 8; ++i) {
#pragma unroll
    for (int j = i + 1; j < 8; ++j) {
      float a = r[i] + r[j];      // s4: (+,+)=a  (+,-)=b  (-,+)=-b  (-,-)=-a
      float bb = r[i] - r[j];
      float dots[4] = { a, bb, -bb, -a };
#pragma unroll
      for (int s4 = 0; s4 < 4; ++s4) {
        float sq = fmaf(-2.f, dots[s4], ssum) + 2.f;
        if (sq < bestSq) { bestSq = sq; bestIdxF = (float)(idx + s4); }
      }
      idx += 4;
    }
  }
  // half-integer roots: dot(c) = sumhr - 2*(Thi[c>>4] + Tlo[c&15]), hr = r/2.
  float hr[8];
#pragma unroll
  for (int d = 0; d < 8; ++d) hr[d] = 0.5f * r[d];
  float sumhr = ((hr[0] + hr[1]) + (hr[2] + hr[3])) + ((hr[4] + hr[5]) + (hr[6] + hr[7]));
  float Thi[16], Tlo[16];
#pragma unroll
  for (int m = 0; m < 16; ++m) {
    float s1 = 0.f, s2 = 0.f;
    if (m & 8) { s1 += hr[0]; s2 += hr[4]; }
    if (m & 4) { s1 += hr[1]; s2 += hr[5]; }
    if (m & 2) { s1 += hr[2]; s2 += hr[6]; }
    if (m & 1) { s1 += hr[3]; s2 += hr[7]; }
    Thi[m] = s1; Tlo[m] = s2;
  }
#pragma unroll
  for (int k = 0; k < 128; ++k) {
    const int c = (k << 1) | (__popc(k) & 1);  // even-parity masks, ascending
    float T = Thi[c >> 4] + Tlo[c & 15];
    float dot = sumhr - 2.f * T;
    float sq = fmaf(-2.f, dot, ssum) + 2.f;
    if (sq < bestSq) { bestSq = sq; bestIdxF = (float)(112 + k); }
  }
  outi[b] = bestIdxF;
}

extern "C" void kernel_launch(void* const* d_in, const int* in_sizes, int n_in,
                              void* d_out, int out_size, void* d_ws, size_t ws_size,
                              hipStream_t stream) {
  const float* colony = (const float*)d_in[0];
  const float* conf   = (const float*)d_in[1];
  const float* Wq     = (const float*)d_in[2];
  const float* bq     = (const float*)d_in[3];
  const float* Wk     = (const float*)d_in[4];
  const float* bk     = (const float*)d_in[5];
  const float* Wv     = (const float*)d_in[6];
  const float* bv     = (const float*)d_in[7];
  const float* comm   = (const float*)d_in[8];
  const float* role   = (const float*)d_in[9];
  const float* mhaw   = (const float*)d_in[10];
  const float* mhab   = (const float*)d_in[11];
  const float* W1     = (const float*)d_in[12];
  const float* b1     = (const float*)d_in[13];
  const float* W2     = (const float*)d_in[14];
  const float* b2     = (const float*)d_in[15];
  const float* gate   = (const float*)d_in[16];

  int B = in_sizes[0] / 56;
  dim3 grid((B + 255) / 256), block(256);
  hipLaunchKernelGGL(e8_kernel, grid, block, 0, stream,
                     colony, conf, Wq, bq, Wk, bk, Wv, bv, comm, role,
                     mhaw, mhab, W1, b1, W2, b2, gate, (float*)d_out, B);
}

// Round 5
// 225.427 us; speedup vs baseline: 3.4984x; 3.4984x over previous
//
#include <hip/hip_runtime.h>
#include <math.h>

#define INV_SQRT2 0.70710678118654752f
#define INV_SQRT32 0.17677669529663689f

// One thread per batch element. Normalized x lives in LDS ([elem][thread]
// layout -> bank = t%32, conflict-free), so the register peak is ~60-70 and
// the allocator cannot spill. LDS caps residency at 2 blocks/CU = 2 waves/EU;
// waves_per_eu(2,2) matches that cap and grants a full 256-reg budget.
__device__ __forceinline__ void nearest_d8(const float* xx, float* y) {
  float f[8], err[8];
#pragma unroll
  for (int d = 0; d < 8; ++d) { f[d] = rintf(xx[d]); err[d] = xx[d] - f[d]; }
  int idx = 0; float best = -1.0f;
#pragma unroll
  for (int d = 0; d < 8; ++d) { float a = fabsf(err[d]); if (a > best) { best = a; idx = d; } }
  float fs = 0.f;
#pragma unroll
  for (int d = 0; d < 8; ++d) fs += f[d];
  bool ok = ((((int)fs) & 1) == 0);
#pragma unroll
  for (int d = 0; d < 8; ++d) {
    float g = f[d] + ((d == idx) ? ((err[d] >= 0.f) ? 1.f : -1.f) : 0.f);
    y[d] = ok ? f[d] : g;
  }
}

extern "C" __global__ void __launch_bounds__(256)
__attribute__((amdgpu_waves_per_eu(2, 2)))
e8_kernel(const float* __restrict__ colony, const float* __restrict__ conf,
          const float* __restrict__ Wq, const float* __restrict__ bq,
          const float* __restrict__ Wk, const float* __restrict__ bk,
          const float* __restrict__ Wv, const float* __restrict__ bv,
          const float* __restrict__ comm, const float* __restrict__ role,
          const float* __restrict__ mha_w, const float* __restrict__ mha_b,
          const float* __restrict__ W1, const float* __restrict__ b1,
          const float* __restrict__ W2, const float* __restrict__ b2,
          const float* __restrict__ gate, float* __restrict__ out, int B)
{
  __shared__ float x_lds[56 * 256];          // [elem e=n*8+d][thread]
  __shared__ float sM8[64], sU[8], sV[8], sCc[1];
  __shared__ float sComm[49], sRole[7];
  __shared__ float sWq3[64], sWk3[64], sBq3[8], sBk3[8];
  __shared__ float sWv[64], sBv[8];
  __shared__ float sW1[256], sB1[32], sW2[256], sB2[8];
  __shared__ float sGate[1];

  const int t = threadIdx.x;
  if (t < 64) {
    int i = t >> 3, j = t & 7;
    float a = 0.f;
    for (int h = 0; h < 32; ++h) a += Wq[h * 8 + i] * Wk[h * 8 + j];
    sM8[t] = a;
    sWq3[t] = mha_w[t];
    sWk3[t] = mha_w[64 + t];
    sWv[t] = Wv[t];
  } else if (t < 72) {
    int j = t - 64;
    float a = 0.f, bb = 0.f;
    for (int h = 0; h < 32; ++h) { a += bq[h] * Wk[h * 8 + j]; bb += bk[h] * Wq[h * 8 + j]; }
    sU[j] = a; sV[j] = bb;
    sBq3[j] = mha_b[j]; sBk3[j] = mha_b[8 + j]; sBv[j] = bv[j]; sB2[j] = b2[j];
  } else if (t == 72) {
    float c = 0.f;
    for (int h = 0; h < 32; ++h) c += bq[h] * bk[h];
    sCc[0] = c;
    sGate[0] = 1.f / (1.f + expf(-gate[0]));
  } else if (t >= 80 && t < 87) {
    int n = t - 80;
    float mx = -1e30f;
    for (int m = 0; m < 7; ++m) mx = fmaxf(mx, comm[n * 7 + m]);
    float e[7], s = 0.f;
    for (int m = 0; m < 7; ++m) { e[m] = expf(comm[n * 7 + m] - mx); s += e[m]; }
    for (int m = 0; m < 7; ++m) sComm[n * 7 + m] = e[m] / s;
  } else if (t == 87) {
    float mx = -1e30f;
    for (int m = 0; m < 7; ++m) mx = fmaxf(mx, role[m]);
    float e[7], s = 0.f;
    for (int m = 0; m < 7; ++m) { e[m] = expf(role[m] - mx); s += e[m]; }
    for (int m = 0; m < 7; ++m) sRole[m] = e[m] / s;
  }
  sW1[t] = W1[t];
  sW2[t] = W2[t];
  if (t < 32) sB1[t] = b1[t];
  __syncthreads();
  // After this point each thread touches only LDS column t -> no more barriers.

  const int b = blockIdx.x * 256 + t;
  if (b >= B) return;

#define LDX(n, j) x_lds[(((n) << 3) + (j)) * 256 + t]

  // ---- load + normalize x; accumulate mean; stash rows in LDS ----
  const float* px = colony + (size_t)b * 56;
  float xm[8];
#pragma unroll
  for (int d = 0; d < 8; ++d) xm[d] = 0.f;
#pragma unroll
  for (int n = 0; n < 7; ++n) {
    float4 v0 = *(const float4*)(px + n * 8);
    float4 v1 = *(const float4*)(px + n * 8 + 4);
    float row[8] = { v0.x, v0.y, v0.z, v0.w, v1.x, v1.y, v1.z, v1.w };
    float ss = 0.f;
#pragma unroll
    for (int d = 0; d < 8; ++d) ss += row[d] * row[d];
    float inv = 1.0f / fmaxf(sqrtf(ss), 1e-12f);
#pragma unroll
    for (int d = 0; d < 8; ++d) {
      row[d] *= inv;
      xm[d] += row[d];
      LDX(n, d) = row[d];
    }
  }
#pragma unroll
  for (int d = 0; d < 8; ++d) xm[d] *= (1.0f / 7.0f);

  // ---- collapsed q.k scores ----
  float w8[8];
#pragma unroll
  for (int j = 0; j < 8; ++j) {
    float a = 0.f;
#pragma unroll
    for (int i = 0; i < 8; ++i) a += xm[i] * sM8[i * 8 + j];
    w8[j] = a + sU[j];
  }
  float base = sCc[0];
#pragma unroll
  for (int i = 0; i < 8; ++i) base += sV[i] * xm[i];
  float sc[7];
#pragma unroll
  for (int n = 0; n < 7; ++n) {
    float a = base;
#pragma unroll
    for (int j = 0; j < 8; ++j) a += w8[j] * LDX(n, j);
    sc[n] = a * INV_SQRT32;
  }
  float sc2[7];
#pragma unroll
  for (int m = 0; m < 7; ++m) {
    float a = 0.f;
#pragma unroll
    for (int n = 0; n < 7; ++n) a += sc[n] * sComm[n * 7 + m];
    sc2[m] = a + sRole[m];
  }

  // ---- tiny 4-head MHA; rows streamed from LDS, K+Q per head in regs ----
  float mhs[7];
#pragma unroll
  for (int m = 0; m < 7; ++m) mhs[m] = 0.f;
#pragma unroll
  for (int h = 0; h < 4; ++h) {
    float Kh[7][2], Qh[7][2];
#pragma unroll
    for (int m = 0; m < 7; ++m) {
      float row[8];
#pragma unroll
      for (int j = 0; j < 8; ++j) row[j] = LDX(m, j);
      float k0 = sBk3[2 * h], k1 = sBk3[2 * h + 1];
      float q0 = sBq3[2 * h], q1 = sBq3[2 * h + 1];
#pragma unroll
      for (int j = 0; j < 8; ++j) {
        k0 += row[j] * sWk3[(2 * h) * 8 + j];
        k1 += row[j] * sWk3[(2 * h + 1) * 8 + j];
        q0 += row[j] * sWq3[(2 * h) * 8 + j];
        q1 += row[j] * sWq3[(2 * h + 1) * 8 + j];
      }
      Kh[m][0] = k0; Kh[m][1] = k1;
      Qh[m][0] = q0; Qh[m][1] = q1;
    }
#pragma unroll
    for (int n = 0; n < 7; ++n) {
      float e[7], mx = -1e30f;
#pragma unroll
      for (int m = 0; m < 7; ++m) {
        float a = Qh[n][0] * Kh[m][0] + Qh[n][1] * Kh[m][1];
        e[m] = a * INV_SQRT2;
        mx = fmaxf(mx, e[m]);
      }
      float s = 0.f;
#pragma unroll
      for (int m = 0; m < 7; ++m) { e[m] = __expf(e[m] - mx); s += e[m]; }
      float inv = 1.0f / s;
#pragma unroll
      for (int m = 0; m < 7; ++m) mhs[m] += e[m] * inv;
    }
  }

  // ---- combine scores, softmax, confidence re-norm ----
  float scf[7], mx = -1e30f;
#pragma unroll
  for (int m = 0; m < 7; ++m) {
    scf[m] = 0.7f * sc2[m] + 0.3f * ((mhs[m] * 0.25f) * (1.0f / 7.0f));
    mx = fmaxf(mx, scf[m]);
  }
  float e[7], s = 0.f;
#pragma unroll
  for (int m = 0; m < 7; ++m) { e[m] = __expf(scf[m] - mx); s += e[m]; }
  float sinv = 1.0f / s;
  float w[7], ws = 0.f;
  const float* pc = conf + (size_t)b * 7;
#pragma unroll
  for (int m = 0; m < 7; ++m) { w[m] = (e[m] * sinv) * pc[m]; ws += w[m]; }
  float dinv = 1.0f / fmaxf(ws, 1e-8f);
#pragma unroll
  for (int m = 0; m < 7; ++m) w[m] = w[m] * dinv;

  // ---- combined = Wv (sum_n w_n x_n) + bv ----
  float xc[8];
#pragma unroll
  for (int d = 0; d < 8; ++d) xc[d] = 0.f;
#pragma unroll
  for (int n = 0; n < 7; ++n) {
#pragma unroll
    for (int d = 0; d < 8; ++d) xc[d] += w[n] * LDX(n, d);
  }
  float comb[8];
#pragma unroll
  for (int i = 0; i < 8; ++i) {
    float a = sBv[i];
#pragma unroll
    for (int j = 0; j < 8; ++j) a += sWv[i * 8 + j] * xc[j];
    comb[i] = a;
  }

  // ---- MLP: gelu(exact) ----
  float o8[8];
#pragma unroll
  for (int i = 0; i < 8; ++i) o8[i] = sB2[i];
#pragma unroll
  for (int i = 0; i < 32; ++i) {
    float a = sB1[i];
#pragma unroll
    for (int j = 0; j < 8; ++j) a += sW1[i * 8 + j] * comb[j];
    float g = 0.5f * a * (1.f + erff(a * INV_SQRT2));
#pragma unroll
    for (int k = 0; k < 8; ++k) o8[k] += sW2[k * 32 + i] * g;
  }

  // ---- refined = norm(combined + sigmoid(gate)*h) ----
  float gsig = sGate[0];
  float pre[8], ss2 = 0.f;
#pragma unroll
  for (int d = 0; d < 8; ++d) { pre[d] = comb[d] + gsig * o8[d]; ss2 += pre[d] * pre[d]; }
  float ninv = 1.0f / fmaxf(sqrtf(ss2), 1e-12f);
  float r[8];
#pragma unroll
  for (int d = 0; d < 8; ++d) r[d] = pre[d] * ninv;

  // ---- nearest E8 point (quantized == hard) ----
  float y0[8], y1[8], xs[8];
  nearest_d8(r, y0);
#pragma unroll
  for (int d = 0; d < 8; ++d) xs[d] = r[d] - 0.5f;
  nearest_d8(xs, y1);
#pragma unroll
  for (int d = 0; d < 8; ++d) y1[d] += 0.5f;
  float d0 = 0.f, d1 = 0.f;
#pragma unroll
  for (int d = 0; d < 8; ++d) {
    float a = r[d] - y0[d], bb = r[d] - y1[d];
    d0 += a * a; d1 += bb * bb;
  }
  bool use0 = (d0 <= d1);

  // ---- store quantized + weights early (kills y0/y1 before argmin tables) ----
  float* outq = out;
  float* outi = out + (size_t)B * 8;
  float* outw = out + (size_t)B * 9;
  {
    float q0v[8];
#pragma unroll
    for (int d = 0; d < 8; ++d) {
      float hd = use0 ? y0[d] : y1[d];
      q0v[d] = r[d] + (hd - r[d]);
    }
    *(float4*)(outq + (size_t)b * 8)     = make_float4(q0v[0], q0v[1], q0v[2], q0v[3]);
    *(float4*)(outq + (size_t)b * 8 + 4) = make_float4(q0v[4], q0v[5], q0v[6], q0v[7]);
  }
#pragma unroll
  for (int m = 0; m < 7; ++m) outw[(size_t)b * 7 + m] = w[m];

  // ---- argmin over 240 E8 roots (first strict min, matches jnp.argmin) ----
  float ssum = 0.f;
#pragma unroll
  for (int d = 0; d < 8; ++d) ssum += r[d] * r[d];
  float bestSq = 1e30f, bestIdxF = 0.f;
  int idx = 0;
#pragma unroll
  for (int i = 0; i < 8; ++i) {
#pragma unroll
    for (int j = i + 1; j < 8; ++j) {
      float a = r[i] + r[j];
      float bb = r[i] - r[j];
      float dots[4] = { a, bb, -bb, -a };
#pragma unroll
      for (int s4 = 0; s4 < 4; ++s4) {
        float sq = fmaf(-2.f, dots[s4], ssum) + 2.f;
        if (sq < bestSq) { bestSq = sq; bestIdxF = (float)(idx + s4); }
      }
      idx += 4;
    }
  }
  float hr[8];
#pragma unroll
  for (int d = 0; d < 8; ++d) hr[d] = 0.5f * r[d];
  float sumhr = ((hr[0] + hr[1]) + (hr[2] + hr[3])) + ((hr[4] + hr[5]) + (hr[6] + hr[7]));
  float Thi[16], Tlo[16];
#pragma unroll
  for (int m = 0; m < 16; ++m) {
    float s1 = 0.f, s2 = 0.f;
    if (m & 8) { s1 += hr[0]; s2 += hr[4]; }
    if (m & 4) { s1 += hr[1]; s2 += hr[5]; }
    if (m & 2) { s1 += hr[2]; s2 += hr[6]; }
    if (m & 1) { s1 += hr[3]; s2 += hr[7]; }
    Thi[m] = s1; Tlo[m] = s2;
  }
#pragma unroll
  for (int k = 0; k < 128; ++k) {
    const int c = (k << 1) | (__popc(k) & 1);
    float T = Thi[c >> 4] + Tlo[c & 15];
    float dot = sumhr - 2.f * T;
    float sq = fmaf(-2.f, dot, ssum) + 2.f;
    if (sq < bestSq) { bestSq = sq; bestIdxF = (float)(112 + k); }
  }
  outi[b] = bestIdxF;
#undef LDX
}

extern "C" void kernel_launch(void* const* d_in, const int* in_sizes, int n_in,
                              void* d_out, int out_size, void* d_ws, size_t ws_size,
                              hipStream_t stream) {
  const float* colony = (const float*)d_in[0];
  const float* conf   = (const float*)d_in[1];
  const float* Wq     = (const float*)d_in[2];
  const float* bq     = (const float*)d_in[3];
  const float* Wk     = (const float*)d_in[4];
  const float* bk     = (const float*)d_in[5];
  const float* Wv     = (const float*)d_in[6];
  const float* bv     = (const float*)d_in[7];
  const float* comm   = (const float*)d_in[8];
  const float* role   = (const float*)d_in[9];
  const float* mhaw   = (const float*)d_in[10];
  const float* mhab   = (const float*)d_in[11];
  const float* W1     = (const float*)d_in[12];
  const float* b1     = (const float*)d_in[13];
  const float* W2     = (const float*)d_in[14];
  const float* b2     = (const float*)d_in[15];
  const float* gate   = (const float*)d_in[16];

  int B = in_sizes[0] / 56;
  dim3 grid((B + 255) / 256), block(256);
  hipLaunchKernelGGL(e8_kernel, grid, block, 0, stream,
                     colony, conf, Wq, bq, Wk, bk, Wv, bv, comm, role,
                     mhaw, mhab, W1, b1, W2, b2, gate, (float*)d_out, B);
}

// Round 6
// 221.364 us; speedup vs baseline: 3.5626x; 1.0184x over previous
//
#include <hip/hip_runtime.h>
#include <math.h>

#define INV_SQRT2 0.70710678118654752f
#define INV_SQRT32 0.17677669529663689f

// One thread per batch element. Normalized x split: rows 0-3 in LDS
// ([elem][thread] layout -> bank = t%32, conflict-free), rows 4-6 in
// registers. LDS/block ~36KB -> 4 blocks/CU = 4 waves/SIMD.
// waves_per_eu(2,2) empirically yields a 128-VGPR budget without the
// allocator's squeeze-to-min spill pathology (rounds 2-4).
__device__ __forceinline__ void nearest_d8(const float* xx, float* y) {
  float f[8], err[8];
#pragma unroll
  for (int d = 0; d < 8; ++d) { f[d] = rintf(xx[d]); err[d] = xx[d] - f[d]; }
  int idx = 0; float best = -1.0f;
#pragma unroll
  for (int d = 0; d < 8; ++d) { float a = fabsf(err[d]); if (a > best) { best = a; idx = d; } }
  float fs = 0.f;
#pragma unroll
  for (int d = 0; d < 8; ++d) fs += f[d];
  bool ok = ((((int)fs) & 1) == 0);
#pragma unroll
  for (int d = 0; d < 8; ++d) {
    float g = f[d] + ((d == idx) ? ((err[d] >= 0.f) ? 1.f : -1.f) : 0.f);
    y[d] = ok ? f[d] : g;
  }
}

extern "C" __global__ void __launch_bounds__(256)
__attribute__((amdgpu_waves_per_eu(2, 2)))
e8_kernel(const float* __restrict__ colony, const float* __restrict__ conf,
          const float* __restrict__ Wq, const float* __restrict__ bq,
          const float* __restrict__ Wk, const float* __restrict__ bk,
          const float* __restrict__ Wv, const float* __restrict__ bv,
          const float* __restrict__ comm, const float* __restrict__ role,
          const float* __restrict__ mha_w, const float* __restrict__ mha_b,
          const float* __restrict__ W1, const float* __restrict__ b1,
          const float* __restrict__ W2, const float* __restrict__ b2,
          const float* __restrict__ gate, float* __restrict__ out, int B)
{
  __shared__ float x_lds[32 * 256];          // rows 0-3: [elem e=n*8+d][thread]
  __shared__ float sM8[64], sU[8], sV[8], sCc[1];
  __shared__ float sComm[49], sRole[7];
  __shared__ float sWq3[64], sWk3[64], sBq3[8], sBk3[8];
  __shared__ float sWv[64], sBv[8];
  __shared__ float sW1[256], sB1[32], sW2[256], sB2[8];
  __shared__ float sGate[1];

  const int t = threadIdx.x;
  if (t < 64) {
    int i = t >> 3, j = t & 7;
    float a = 0.f;
    for (int h = 0; h < 32; ++h) a += Wq[h * 8 + i] * Wk[h * 8 + j];
    sM8[t] = a;
    sWq3[t] = mha_w[t];
    sWk3[t] = mha_w[64 + t];
    sWv[t] = Wv[t];
  } else if (t < 72) {
    int j = t - 64;
    float a = 0.f, bb = 0.f;
    for (int h = 0; h < 32; ++h) { a += bq[h] * Wk[h * 8 + j]; bb += bk[h] * Wq[h * 8 + j]; }
    sU[j] = a; sV[j] = bb;
    sBq3[j] = mha_b[j]; sBk3[j] = mha_b[8 + j]; sBv[j] = bv[j]; sB2[j] = b2[j];
  } else if (t == 72) {
    float c = 0.f;
    for (int h = 0; h < 32; ++h) c += bq[h] * bk[h];
    sCc[0] = c;
    sGate[0] = 1.f / (1.f + expf(-gate[0]));
  } else if (t >= 80 && t < 87) {
    int n = t - 80;
    float mx = -1e30f;
    for (int m = 0; m < 7; ++m) mx = fmaxf(mx, comm[n * 7 + m]);
    float e[7], s = 0.f;
    for (int m = 0; m < 7; ++m) { e[m] = expf(comm[n * 7 + m] - mx); s += e[m]; }
    for (int m = 0; m < 7; ++m) sComm[n * 7 + m] = e[m] / s;
  } else if (t == 87) {
    float mx = -1e30f;
    for (int m = 0; m < 7; ++m) mx = fmaxf(mx, role[m]);
    float e[7], s = 0.f;
    for (int m = 0; m < 7; ++m) { e[m] = expf(role[m] - mx); s += e[m]; }
    for (int m = 0; m < 7; ++m) sRole[m] = e[m] / s;
  }
  sW1[t] = W1[t];
  sW2[t] = W2[t];
  if (t < 32) sB1[t] = b1[t];
  __syncthreads();
  // After this point each thread touches only LDS column t -> no more barriers.

  const int b = blockIdx.x * 256 + t;
  if (b >= B) return;

  float xr[3][8];   // rows 4-6 in registers
#define XGET(n, j) ((n) < 4 ? x_lds[(((n) << 3) + (j)) * 256 + t] : xr[(n) - 4][(j)])

  // ---- load + normalize x; accumulate mean; stash rows ----
  const float* px = colony + (size_t)b * 56;
  float xm[8];
#pragma unroll
  for (int d = 0; d < 8; ++d) xm[d] = 0.f;
#pragma unroll
  for (int n = 0; n < 7; ++n) {
    float4 v0 = *(const float4*)(px + n * 8);
    float4 v1 = *(const float4*)(px + n * 8 + 4);
    float row[8] = { v0.x, v0.y, v0.z, v0.w, v1.x, v1.y, v1.z, v1.w };
    float ss = 0.f;
#pragma unroll
    for (int d = 0; d < 8; ++d) ss += row[d] * row[d];
    float inv = 1.0f / fmaxf(sqrtf(ss), 1e-12f);
#pragma unroll
    for (int d = 0; d < 8; ++d) {
      row[d] *= inv;
      xm[d] += row[d];
      if (n < 4) x_lds[((n << 3) + d) * 256 + t] = row[d];
      else       xr[n - 4][d] = row[d];
    }
  }
#pragma unroll
  for (int d = 0; d < 8; ++d) xm[d] *= (1.0f / 7.0f);

  // ---- collapsed q.k scores ----
  float w8[8];
#pragma unroll
  for (int j = 0; j < 8; ++j) {
    float a = 0.f;
#pragma unroll
    for (int i = 0; i < 8; ++i) a += xm[i] * sM8[i * 8 + j];
    w8[j] = a + sU[j];
  }
  float base = sCc[0];
#pragma unroll
  for (int i = 0; i < 8; ++i) base += sV[i] * xm[i];
  float sc[7];
#pragma unroll
  for (int n = 0; n < 7; ++n) {
    float a = base;
#pragma unroll
    for (int j = 0; j < 8; ++j) a += w8[j] * XGET(n, j);
    sc[n] = a * INV_SQRT32;
  }
  float sc2[7];
#pragma unroll
  for (int m = 0; m < 7; ++m) {
    float a = 0.f;
#pragma unroll
    for (int n = 0; n < 7; ++n) a += sc[n] * sComm[n * 7 + m];
    sc2[m] = a + sRole[m];
  }

  // ---- tiny 4-head MHA; K+Q per head in regs, rows streamed via XGET ----
  float mhs[7];
#pragma unroll
  for (int m = 0; m < 7; ++m) mhs[m] = 0.f;
#pragma unroll
  for (int h = 0; h < 4; ++h) {
    float Kh[7][2], Qh[7][2];
#pragma unroll
    for (int m = 0; m < 7; ++m) {
      float row[8];
#pragma unroll
      for (int j = 0; j < 8; ++j) row[j] = XGET(m, j);
      float k0 = sBk3[2 * h], k1 = sBk3[2 * h + 1];
      float q0 = sBq3[2 * h], q1 = sBq3[2 * h + 1];
#pragma unroll
      for (int j = 0; j < 8; ++j) {
        k0 += row[j] * sWk3[(2 * h) * 8 + j];
        k1 += row[j] * sWk3[(2 * h + 1) * 8 + j];
        q0 += row[j] * sWq3[(2 * h) * 8 + j];
        q1 += row[j] * sWq3[(2 * h + 1) * 8 + j];
      }
      Kh[m][0] = k0; Kh[m][1] = k1;
      Qh[m][0] = q0; Qh[m][1] = q1;
    }
#pragma unroll
    for (int n = 0; n < 7; ++n) {
      float e[7], mx = -1e30f;
#pragma unroll
      for (int m = 0; m < 7; ++m) {
        float a = Qh[n][0] * Kh[m][0] + Qh[n][1] * Kh[m][1];
        e[m] = a * INV_SQRT2;
        mx = fmaxf(mx, e[m]);
      }
      float s = 0.f;
#pragma unroll
      for (int m = 0; m < 7; ++m) { e[m] = __expf(e[m] - mx); s += e[m]; }
      float inv = 1.0f / s;
#pragma unroll
      for (int m = 0; m < 7; ++m) mhs[m] += e[m] * inv;
    }
  }

  // ---- combine scores, softmax, confidence re-norm ----
  float scf[7], mx = -1e30f;
#pragma unroll
  for (int m = 0; m < 7; ++m) {
    scf[m] = 0.7f * sc2[m] + 0.3f * ((mhs[m] * 0.25f) * (1.0f / 7.0f));
    mx = fmaxf(mx, scf[m]);
  }
  float e[7], s = 0.f;
#pragma unroll
  for (int m = 0; m < 7; ++m) { e[m] = __expf(scf[m] - mx); s += e[m]; }
  float sinv = 1.0f / s;
  float w[7], ws = 0.f;
  const float* pc = conf + (size_t)b * 7;
#pragma unroll
  for (int m = 0; m < 7; ++m) { w[m] = (e[m] * sinv) * pc[m]; ws += w[m]; }
  float dinv = 1.0f / fmaxf(ws, 1e-8f);
#pragma unroll
  for (int m = 0; m < 7; ++m) w[m] = w[m] * dinv;

  // ---- combined = Wv (sum_n w_n x_n) + bv ----
  float xc[8];
#pragma unroll
  for (int d = 0; d < 8; ++d) xc[d] = 0.f;
#pragma unroll
  for (int n = 0; n < 7; ++n) {
#pragma unroll
    for (int d = 0; d < 8; ++d) xc[d] += w[n] * XGET(n, d);
  }
  float comb[8];
#pragma unroll
  for (int i = 0; i < 8; ++i) {
    float a = sBv[i];
#pragma unroll
    for (int j = 0; j < 8; ++j) a += sWv[i * 8 + j] * xc[j];
    comb[i] = a;
  }

  // ---- MLP: gelu(exact) ----
  float o8[8];
#pragma unroll
  for (int i = 0; i < 8; ++i) o8[i] = sB2[i];
#pragma unroll
  for (int i = 0; i < 32; ++i) {
    float a = sB1[i];
#pragma unroll
    for (int j = 0; j < 8; ++j) a += sW1[i * 8 + j] * comb[j];
    float g = 0.5f * a * (1.f + erff(a * INV_SQRT2));
#pragma unroll
    for (int k = 0; k < 8; ++k) o8[k] += sW2[k * 32 + i] * g;
  }

  // ---- refined = norm(combined + sigmoid(gate)*h) ----
  float gsig = sGate[0];
  float pre[8], ss2 = 0.f;
#pragma unroll
  for (int d = 0; d < 8; ++d) { pre[d] = comb[d] + gsig * o8[d]; ss2 += pre[d] * pre[d]; }
  float ninv = 1.0f / fmaxf(sqrtf(ss2), 1e-12f);
  float r[8];
#pragma unroll
  for (int d = 0; d < 8; ++d) r[d] = pre[d] * ninv;

  // ---- nearest E8 point (quantized == hard) ----
  float y0[8], y1[8], xs[8];
  nearest_d8(r, y0);
#pragma unroll
  for (int d = 0; d < 8; ++d) xs[d] = r[d] - 0.5f;
  nearest_d8(xs, y1);
#pragma unroll
  for (int d = 0; d < 8; ++d) y1[d] += 0.5f;
  float d0 = 0.f, d1 = 0.f;
#pragma unroll
  for (int d = 0; d < 8; ++d) {
    float a = r[d] - y0[d], bb = r[d] - y1[d];
    d0 += a * a; d1 += bb * bb;
  }
  bool use0 = (d0 <= d1);

  // ---- store quantized + weights early (kills y0/y1 before argmin tables) ----
  float* outq = out;
  float* outi = out + (size_t)B * 8;
  float* outw = out + (size_t)B * 9;
  {
    float q0v[8];
#pragma unroll
    for (int d = 0; d < 8; ++d) {
      float hd = use0 ? y0[d] : y1[d];
      q0v[d] = r[d] + (hd - r[d]);
    }
    *(float4*)(outq + (size_t)b * 8)     = make_float4(q0v[0], q0v[1], q0v[2], q0v[3]);
    *(float4*)(outq + (size_t)b * 8 + 4) = make_float4(q0v[4], q0v[5], q0v[6], q0v[7]);
  }
#pragma unroll
  for (int m = 0; m < 7; ++m) outw[(size_t)b * 7 + m] = w[m];

  // ---- argmin over 240 E8 roots (first strict min, matches jnp.argmin) ----
  float ssum = 0.f;
#pragma unroll
  for (int d = 0; d < 8; ++d) ssum += r[d] * r[d];
  float bestSq = 1e30f, bestIdxF = 0.f;
  int idx = 0;
#pragma unroll
  for (int i = 0; i < 8; ++i) {
#pragma unroll
    for (int j = i + 1; j < 8; ++j) {
      float a = r[i] + r[j];
      float bb = r[i] - r[j];
      float dots[4] = { a, bb, -bb, -a };
#pragma unroll
      for (int s4 = 0; s4 < 4; ++s4) {
        float sq = fmaf(-2.f, dots[s4], ssum) + 2.f;
        if (sq < bestSq) { bestSq = sq; bestIdxF = (float)(idx + s4); }
      }
      idx += 4;
    }
  }
  float hr[8];
#pragma unroll
  for (int d = 0; d < 8; ++d) hr[d] = 0.5f * r[d];
  float sumhr = ((hr[0] + hr[1]) + (hr[2] + hr[3])) + ((hr[4] + hr[5]) + (hr[6] + hr[7]));
  float Thi[16], Tlo[16];
#pragma unroll
  for (int m = 0; m < 16; ++m) {
    float s1 = 0.f, s2 = 0.f;
    if (m & 8) { s1 += hr[0]; s2 += hr[4]; }
    if (m & 4) { s1 += hr[1]; s2 += hr[5]; }
    if (m & 2) { s1 += hr[2]; s2 += hr[6]; }
    if (m & 1) { s1 += hr[3]; s2 += hr[7]; }
    Thi[m] = s1; Tlo[m] = s2;
  }
#pragma unroll
  for (int k = 0; k < 128; ++k) {
    const int c = (k << 1) | (__popc(k) & 1);
    float T = Thi[c >> 4] + Tlo[c & 15];
    float dot = sumhr - 2.f * T;
    float sq = fmaf(-2.f, dot, ssum) + 2.f;
    if (sq < bestSq) { bestSq = sq; bestIdxF = (float)(112 + k); }
  }
  outi[b] = bestIdxF;
#undef XGET
}

extern "C" void kernel_launch(void* const* d_in, const int* in_sizes, int n_in,
                              void* d_out, int out_size, void* d_ws, size_t ws_size,
                              hipStream_t stream) {
  const float* colony = (const float*)d_in[0];
  const float* conf   = (const float*)d_in[1];
  const float* Wq     = (const float*)d_in[2];
  const float* bq     = (const float*)d_in[3];
  const float* Wk     = (const float*)d_in[4];
  const float* bk     = (const float*)d_in[5];
  const float* Wv     = (const float*)d_in[6];
  const float* bv     = (const float*)d_in[7];
  const float* comm   = (const float*)d_in[8];
  const float* role   = (const float*)d_in[9];
  const float* mhaw   = (const float*)d_in[10];
  const float* mhab   = (const float*)d_in[11];
  const float* W1     = (const float*)d_in[12];
  const float* b1     = (const float*)d_in[13];
  const float* W2     = (const float*)d_in[14];
  const float* b2     = (const float*)d_in[15];
  const float* gate   = (const float*)d_in[16];

  int B = in_sizes[0] / 56;
  dim3 grid((B + 255) / 256), block(256);
  hipLaunchKernelGGL(e8_kernel, grid, block, 0, stream,
                     colony, conf, Wq, bq, Wk, bk, Wv, bv, comm, role,
                     mhaw, mhab, W1, b1, W2, b2, gate, (float*)d_out, B);
}

// Round 7
// 173.466 us; speedup vs baseline: 4.5463x; 1.2761x over previous
//
#include <hip/hip_runtime.h>
#include <math.h>

#define INV_SQRT2 0.70710678118654752f
#define INV_SQRT32 0.17677669529663689f

// One thread per batch element. x rows 0-2 in LDS ([elem][thread] -> bank=t%32,
// conflict-free), rows 3-6 in registers. Weights output staged via LDS for
// fully-coalesced stores. NO occupancy attributes: rounds 2-6 showed every
// min-waves hint makes the backend over-squeeze VGPRs and spill to scratch
// (+100MB fetch/+170MB write); unconstrained allocation (round 1) never spilled.
__device__ __forceinline__ void nearest_d8(const float* xx, float* y) {
  float f[8], err[8];
#pragma unroll
  for (int d = 0; d < 8; ++d) { f[d] = rintf(xx[d]); err[d] = xx[d] - f[d]; }
  int idx = 0; float best = -1.0f;
#pragma unroll
  for (int d = 0; d < 8; ++d) { float a = fabsf(err[d]); if (a > best) { best = a; idx = d; } }
  float fs = 0.f;
#pragma unroll
  for (int d = 0; d < 8; ++d) fs += f[d];
  bool ok = ((((int)fs) & 1) == 0);
#pragma unroll
  for (int d = 0; d < 8; ++d) {
    float g = f[d] + ((d == idx) ? ((err[d] >= 0.f) ? 1.f : -1.f) : 0.f);
    y[d] = ok ? f[d] : g;
  }
}

extern "C" __global__ void __launch_bounds__(256)
e8_kernel(const float* __restrict__ colony, const float* __restrict__ conf,
          const float* __restrict__ Wq, const float* __restrict__ bq,
          const float* __restrict__ Wk, const float* __restrict__ bk,
          const float* __restrict__ Wv, const float* __restrict__ bv,
          const float* __restrict__ comm, const float* __restrict__ role,
          const float* __restrict__ mha_w, const float* __restrict__ mha_b,
          const float* __restrict__ W1, const float* __restrict__ b1,
          const float* __restrict__ W2, const float* __restrict__ b2,
          const float* __restrict__ gate, float* __restrict__ out, int B)
{
  __shared__ float x_lds[24 * 256];          // x rows 0-2: [elem e=n*8+d][thread]
  __shared__ float wlds[7 * 256];            // linear image of this block's outw region
  __shared__ float sM8[64], sU[8], sV[8], sCc[1];
  __shared__ float sComm[49], sRole[7];
  __shared__ float sWq3[64], sWk3[64], sBq3[8], sBk3[8];
  __shared__ float sWv[64], sBv[8];
  __shared__ float sW1[256], sB1[32], sW2[256], sB2[8];
  __shared__ float sGate[1];

  const int t = threadIdx.x;
  if (t < 64) {
    int i = t >> 3, j = t & 7;
    float a = 0.f;
    for (int h = 0; h < 32; ++h) a += Wq[h * 8 + i] * Wk[h * 8 + j];
    sM8[t] = a;
    sWq3[t] = mha_w[t];
    sWk3[t] = mha_w[64 + t];
    sWv[t] = Wv[t];
  } else if (t < 72) {
    int j = t - 64;
    float a = 0.f, bb = 0.f;
    for (int h = 0; h < 32; ++h) { a += bq[h] * Wk[h * 8 + j]; bb += bk[h] * Wq[h * 8 + j]; }
    sU[j] = a; sV[j] = bb;
    sBq3[j] = mha_b[j]; sBk3[j] = mha_b[8 + j]; sBv[j] = bv[j]; sB2[j] = b2[j];
  } else if (t == 72) {
    float c = 0.f;
    for (int h = 0; h < 32; ++h) c += bq[h] * bk[h];
    sCc[0] = c;
    sGate[0] = 1.f / (1.f + expf(-gate[0]));
  } else if (t >= 80 && t < 87) {
    int n = t - 80;
    float mx = -1e30f;
    for (int m = 0; m < 7; ++m) mx = fmaxf(mx, comm[n * 7 + m]);
    float e[7], s = 0.f;
    for (int m = 0; m < 7; ++m) { e[m] = expf(comm[n * 7 + m] - mx); s += e[m]; }
    for (int m = 0; m < 7; ++m) sComm[n * 7 + m] = e[m] / s;
  } else if (t == 87) {
    float mx = -1e30f;
    for (int m = 0; m < 7; ++m) mx = fmaxf(mx, role[m]);
    float e[7], s = 0.f;
    for (int m = 0; m < 7; ++m) { e[m] = expf(role[m] - mx); s += e[m]; }
    for (int m = 0; m < 7; ++m) sRole[m] = e[m] / s;
  }
  sW1[t] = W1[t];
  sW2[t] = W2[t];
  if (t < 32) sB1[t] = b1[t];
  __syncthreads();

  const int b = blockIdx.x * 256 + t;
  const bool fullblk = ((blockIdx.x + 1) * 256u <= (unsigned)B);
  if (b >= B) return;

  float xr[4][8];   // x rows 3-6 in registers
#define XGET(n, j) ((n) < 3 ? x_lds[(((n) << 3) + (j)) * 256 + t] : xr[(n) - 3][(j)])

  // ---- load + normalize x; accumulate mean; stash rows ----
  const float* px = colony + (size_t)b * 56;
  float xm[8];
#pragma unroll
  for (int d = 0; d < 8; ++d) xm[d] = 0.f;
#pragma unroll
  for (int n = 0; n < 7; ++n) {
    float4 v0 = *(const float4*)(px + n * 8);
    float4 v1 = *(const float4*)(px + n * 8 + 4);
    float row[8] = { v0.x, v0.y, v0.z, v0.w, v1.x, v1.y, v1.z, v1.w };
    float ss = 0.f;
#pragma unroll
    for (int d = 0; d < 8; ++d) ss += row[d] * row[d];
    float inv = 1.0f / fmaxf(sqrtf(ss), 1e-12f);
#pragma unroll
    for (int d = 0; d < 8; ++d) {
      row[d] *= inv;
      xm[d] += row[d];
      if (n < 3) x_lds[((n << 3) + d) * 256 + t] = row[d];
      else       xr[n - 3][d] = row[d];
    }
  }
#pragma unroll
  for (int d = 0; d < 8; ++d) xm[d] *= (1.0f / 7.0f);

  // ---- collapsed q.k scores ----
  float w8[8];
#pragma unroll
  for (int j = 0; j < 8; ++j) {
    float a = 0.f;
#pragma unroll
    for (int i = 0; i < 8; ++i) a += xm[i] * sM8[i * 8 + j];
    w8[j] = a + sU[j];
  }
  float base = sCc[0];
#pragma unroll
  for (int i = 0; i < 8; ++i) base += sV[i] * xm[i];
  float sc[7];
#pragma unroll
  for (int n = 0; n < 7; ++n) {
    float a = base;
#pragma unroll
    for (int j = 0; j < 8; ++j) a += w8[j] * XGET(n, j);
    sc[n] = a * INV_SQRT32;
  }
  float sc2[7];
#pragma unroll
  for (int m = 0; m < 7; ++m) {
    float a = 0.f;
#pragma unroll
    for (int n = 0; n < 7; ++n) a += sc[n] * sComm[n * 7 + m];
    sc2[m] = a + sRole[m];
  }

  // ---- tiny 4-head MHA; K+Q per head in regs, rows streamed via XGET ----
  float mhs[7];
#pragma unroll
  for (int m = 0; m < 7; ++m) mhs[m] = 0.f;
#pragma unroll
  for (int h = 0; h < 4; ++h) {
    float Kh[7][2], Qh[7][2];
#pragma unroll
    for (int m = 0; m < 7; ++m) {
      float row[8];
#pragma unroll
      for (int j = 0; j < 8; ++j) row[j] = XGET(m, j);
      float k0 = sBk3[2 * h], k1 = sBk3[2 * h + 1];
      float q0 = sBq3[2 * h], q1 = sBq3[2 * h + 1];
#pragma unroll
      for (int j = 0; j < 8; ++j) {
        k0 += row[j] * sWk3[(2 * h) * 8 + j];
        k1 += row[j] * sWk3[(2 * h + 1) * 8 + j];
        q0 += row[j] * sWq3[(2 * h) * 8 + j];
        q1 += row[j] * sWq3[(2 * h + 1) * 8 + j];
      }
      Kh[m][0] = k0; Kh[m][1] = k1;
      Qh[m][0] = q0; Qh[m][1] = q1;
    }
#pragma unroll
    for (int n = 0; n < 7; ++n) {
      float e[7], mx = -1e30f;
#pragma unroll
      for (int m = 0; m < 7; ++m) {
        float a = Qh[n][0] * Kh[m][0] + Qh[n][1] * Kh[m][1];
        e[m] = a * INV_SQRT2;
        mx = fmaxf(mx, e[m]);
      }
      float s = 0.f;
#pragma unroll
      for (int m = 0; m < 7; ++m) { e[m] = __expf(e[m] - mx); s += e[m]; }
      float inv = 1.0f / s;
#pragma unroll
      for (int m = 0; m < 7; ++m) mhs[m] += e[m] * inv;
    }
  }

  // ---- combine scores, softmax, confidence re-norm ----
  float scf[7], mx = -1e30f;
#pragma unroll
  for (int m = 0; m < 7; ++m) {
    scf[m] = 0.7f * sc2[m] + 0.3f * ((mhs[m] * 0.25f) * (1.0f / 7.0f));
    mx = fmaxf(mx, scf[m]);
  }
  float e[7], s = 0.f;
#pragma unroll
  for (int m = 0; m < 7; ++m) { e[m] = __expf(scf[m] - mx); s += e[m]; }
  float sinv = 1.0f / s;
  float w[7], ws = 0.f;
  const float* pc = conf + (size_t)b * 7;
#pragma unroll
  for (int m = 0; m < 7; ++m) { w[m] = (e[m] * sinv) * pc[m]; ws += w[m]; }
  float dinv = 1.0f / fmaxf(ws, 1e-8f);
#pragma unroll
  for (int m = 0; m < 7; ++m) w[m] = w[m] * dinv;

  float* outq = out;
  float* outi = out + (size_t)B * 8;
  float* outw = out + (size_t)B * 9;

  // ---- combined = Wv (sum_n w_n x_n) + bv ----
  float xc[8];
#pragma unroll
  for (int d = 0; d < 8; ++d) xc[d] = 0.f;
#pragma unroll
  for (int n = 0; n < 7; ++n) {
#pragma unroll
    for (int d = 0; d < 8; ++d) xc[d] += w[n] * XGET(n, d);
  }

  // ---- stage weights now: frees w[] registers for the rest of the kernel ----
  if (fullblk) {
#pragma unroll
    for (int m = 0; m < 7; ++m) wlds[t * 7 + m] = w[m];
  } else {
#pragma unroll
    for (int m = 0; m < 7; ++m) outw[(size_t)b * 7 + m] = w[m];
  }

  float comb[8];
#pragma unroll
  for (int i = 0; i < 8; ++i) {
    float a = sBv[i];
#pragma unroll
    for (int j = 0; j < 8; ++j) a += sWv[i * 8 + j] * xc[j];
    comb[i] = a;
  }

  // ---- MLP: gelu(exact) ----
  float o8[8];
#pragma unroll
  for (int i = 0; i < 8; ++i) o8[i] = sB2[i];
#pragma unroll
  for (int i = 0; i < 32; ++i) {
    float a = sB1[i];
#pragma unroll
    for (int j = 0; j < 8; ++j) a += sW1[i * 8 + j] * comb[j];
    float g = 0.5f * a * (1.f + erff(a * INV_SQRT2));
#pragma unroll
    for (int k = 0; k < 8; ++k) o8[k] += sW2[k * 32 + i] * g;
  }

  // ---- refined = norm(combined + sigmoid(gate)*h) ----
  float gsig = sGate[0];
  float pre[8], ss2 = 0.f;
#pragma unroll
  for (int d = 0; d < 8; ++d) { pre[d] = comb[d] + gsig * o8[d]; ss2 += pre[d] * pre[d]; }
  float ninv = 1.0f / fmaxf(sqrtf(ss2), 1e-12f);
  float r[8];
#pragma unroll
  for (int d = 0; d < 8; ++d) r[d] = pre[d] * ninv;

  // ---- nearest E8 point (quantized == hard) ----
  float y0[8], y1[8], xs[8];
  nearest_d8(r, y0);
#pragma unroll
  for (int d = 0; d < 8; ++d) xs[d] = r[d] - 0.5f;
  nearest_d8(xs, y1);
#pragma unroll
  for (int d = 0; d < 8; ++d) y1[d] += 0.5f;
  float d0 = 0.f, d1 = 0.f;
#pragma unroll
  for (int d = 0; d < 8; ++d) {
    float a = r[d] - y0[d], bb = r[d] - y1[d];
    d0 += a * a; d1 += bb * bb;
  }
  bool use0 = (d0 <= d1);

  // ---- store quantized early (kills y0/y1 before argmin tables) ----
  {
    float q0v[8];
#pragma unroll
    for (int d = 0; d < 8; ++d) {
      float hd = use0 ? y0[d] : y1[d];
      q0v[d] = r[d] + (hd - r[d]);
    }
    *(float4*)(outq + (size_t)b * 8)     = make_float4(q0v[0], q0v[1], q0v[2], q0v[3]);
    *(float4*)(outq + (size_t)b * 8 + 4) = make_float4(q0v[4], q0v[5], q0v[6], q0v[7]);
  }

  // ---- argmin over 240 E8 roots (first strict min, matches jnp.argmin) ----
  float ssum = 0.f;
#pragma unroll
  for (int d = 0; d < 8; ++d) ssum += r[d] * r[d];
  float bestSq = 1e30f, bestIdxF = 0.f;
  int idx = 0;
#pragma unroll
  for (int i = 0; i < 8; ++i) {
#pragma unroll
    for (int j = i + 1; j < 8; ++j) {
      float a = r[i] + r[j];
      float bb = r[i] - r[j];
      float dots[4] = { a, bb, -bb, -a };
#pragma unroll
      for (int s4 = 0; s4 < 4; ++s4) {
        float sq = fmaf(-2.f, dots[s4], ssum) + 2.f;
        if (sq < bestSq) { bestSq = sq; bestIdxF = (float)(idx + s4); }
      }
      idx += 4;
    }
  }
  float hr[8];
#pragma unroll
  for (int d = 0; d < 8; ++d) hr[d] = 0.5f * r[d];
  float sumhr = ((hr[0] + hr[1]) + (hr[2] + hr[3])) + ((hr[4] + hr[5]) + (hr[6] + hr[7]));
  float Thi[16], Tlo[16];
#pragma unroll
  for (int m = 0; m < 16; ++m) {
    float s1 = 0.f, s2 = 0.f;
    if (m & 8) { s1 += hr[0]; s2 += hr[4]; }
    if (m & 4) { s1 += hr[1]; s2 += hr[5]; }
    if (m & 2) { s1 += hr[2]; s2 += hr[6]; }
    if (m & 1) { s1 += hr[3]; s2 += hr[7]; }
    Thi[m] = s1; Tlo[m] = s2;
  }
#pragma unroll
  for (int k = 0; k < 128; ++k) {
    const int c = (k << 1) | (__popc(k) & 1);
    float T = Thi[c >> 4] + Tlo[c & 15];
    float dot = sumhr - 2.f * T;
    float sq = fmaf(-2.f, dot, ssum) + 2.f;
    if (sq < bestSq) { bestSq = sq; bestIdxF = (float)(112 + k); }
  }
  outi[b] = bestIdxF;

  // ---- coalesced weights store: 7 x 256-dword contiguous chunks ----
  if (fullblk) {
    __syncthreads();   // all threads of a full block reach here
    float* dst = outw + (size_t)blockIdx.x * 1792;
#pragma unroll
    for (int k = 0; k < 7; ++k) dst[k * 256 + t] = wlds[k * 256 + t];
  }
#undef XGET
}

extern "C" void kernel_launch(void* const* d_in, const int* in_sizes, int n_in,
                              void* d_out, int out_size, void* d_ws, size_t ws_size,
                              hipStream_t stream) {
  const float* colony = (const float*)d_in[0];
  const float* conf   = (const float*)d_in[1];
  const float* Wq     = (const float*)d_in[2];
  const float* bq     = (const float*)d_in[3];
  const float* Wk     = (const float*)d_in[4];
  const float* bk     = (const float*)d_in[5];
  const float* Wv     = (const float*)d_in[6];
  const float* bv     = (const float*)d_in[7];
  const float* comm   = (const float*)d_in[8];
  const float* role   = (const float*)d_in[9];
  const float* mhaw   = (const float*)d_in[10];
  const float* mhab   = (const float*)d_in[11];
  const float* W1     = (const float*)d_in[12];
  const float* b1     = (const float*)d_in[13];
  const float* W2     = (const float*)d_in[14];
  const float* b2     = (const float*)d_in[15];
  const float* gate   = (const float*)d_in[16];

  int B = in_sizes[0] / 56;
  dim3 grid((B + 255) / 256), block(256);
  hipLaunchKernelGGL(e8_kernel, grid, block, 0, stream,
                     colony, conf, Wq, bq, Wk, bk, Wv, bv, comm, role,
                     mhaw, mhab, W1, b1, W2, b2, gate, (float*)d_out, B);
}

// Round 8
// 164.704 us; speedup vs baseline: 4.7882x; 1.0532x over previous
//
#include <hip/hip_runtime.h>
#include <math.h>

#define INV_SQRT2 0.70710678118654752f
#define INV_SQRT32 0.17677669529663689f

// 2 threads per element (lane pair t, t^1; half = t&1). 256 thr/block ->
// 128 elements/block. x lives fully in LDS [feature][elem] (bank = elem%32,
// pair lanes broadcast same address -> conflict-free). Work split across the
// pair with UNIFORM control flow: MHA heads 2+2, MLP neurons 16+16, integer
// argmin roots by sign-pair; everything order-sensitive is computed
// redundantly in ref-sequential order on both lanes. Pair combines via
// __shfl_xor with canonical (even+odd) ordering so both lanes stay
// bit-identical. No occupancy attributes (rounds 2-6: hints => spill).
__device__ __forceinline__ void nearest_d8(const float* xx, float* y) {
  float f[8], err[8];
#pragma unroll
  for (int d = 0; d < 8; ++d) { f[d] = rintf(xx[d]); err[d] = xx[d] - f[d]; }
  int idx = 0; float best = -1.0f;
#pragma unroll
  for (int d = 0; d < 8; ++d) { float a = fabsf(err[d]); if (a > best) { best = a; idx = d; } }
  float fs = 0.f;
#pragma unroll
  for (int d = 0; d < 8; ++d) fs += f[d];
  bool ok = ((((int)fs) & 1) == 0);
#pragma unroll
  for (int d = 0; d < 8; ++d) {
    float g = f[d] + ((d == idx) ? ((err[d] >= 0.f) ? 1.f : -1.f) : 0.f);
    y[d] = ok ? f[d] : g;
  }
}

// canonical pair sum: both lanes compute (even_part + odd_part) -> identical bits
__device__ __forceinline__ float pair_sum(float mine, int half) {
  float o = __shfl_xor(mine, 1, 64);
  return half ? (o + mine) : (mine + o);
}

extern "C" __global__ void __launch_bounds__(256)
e8_kernel(const float* __restrict__ colony, const float* __restrict__ conf,
          const float* __restrict__ Wq, const float* __restrict__ bq,
          const float* __restrict__ Wk, const float* __restrict__ bk,
          const float* __restrict__ Wv, const float* __restrict__ bv,
          const float* __restrict__ comm, const float* __restrict__ role,
          const float* __restrict__ mha_w, const float* __restrict__ mha_b,
          const float* __restrict__ W1, const float* __restrict__ b1,
          const float* __restrict__ W2, const float* __restrict__ b2,
          const float* __restrict__ gate, float* __restrict__ out, int B)
{
  __shared__ float x_lds[56 * 128];   // [feature n*8+d][elem]
  __shared__ float wlds[7 * 128];     // block's outw image for coalesced store
  __shared__ float sM8[64], sU[8], sV[8], sCc[1];
  __shared__ float sComm[49], sRole[7];
  __shared__ float sWq3[64], sWk3[64], sBq3[8], sBk3[8];
  __shared__ float sWv[64], sBv[8];
  __shared__ float sW1[256], sB1[32], sW2[256], sB2[8];
  __shared__ float sGate[1];

  const int t = threadIdx.x;
  if (t < 64) {
    int i = t >> 3, j = t & 7;
    float a = 0.f;
    for (int h = 0; h < 32; ++h) a += Wq[h * 8 + i] * Wk[h * 8 + j];
    sM8[t] = a;
    sWq3[t] = mha_w[t];
    sWk3[t] = mha_w[64 + t];
    sWv[t] = Wv[t];
  } else if (t < 72) {
    int j = t - 64;
    float a = 0.f, bb = 0.f;
    for (int h = 0; h < 32; ++h) { a += bq[h] * Wk[h * 8 + j]; bb += bk[h] * Wq[h * 8 + j]; }
    sU[j] = a; sV[j] = bb;
    sBq3[j] = mha_b[j]; sBk3[j] = mha_b[8 + j]; sBv[j] = bv[j]; sB2[j] = b2[j];
  } else if (t == 72) {
    float c = 0.f;
    for (int h = 0; h < 32; ++h) c += bq[h] * bk[h];
    sCc[0] = c;
    sGate[0] = 1.f / (1.f + expf(-gate[0]));
  } else if (t >= 80 && t < 87) {
    int n = t - 80;
    float mx = -1e30f;
    for (int m = 0; m < 7; ++m) mx = fmaxf(mx, comm[n * 7 + m]);
    float ee[7], s = 0.f;
    for (int m = 0; m < 7; ++m) { ee[m] = expf(comm[n * 7 + m] - mx); s += ee[m]; }
    for (int m = 0; m < 7; ++m) sComm[n * 7 + m] = ee[m] / s;
  } else if (t == 87) {
    float mx = -1e30f;
    for (int m = 0; m < 7; ++m) mx = fmaxf(mx, role[m]);
    float ee[7], s = 0.f;
    for (int m = 0; m < 7; ++m) { ee[m] = expf(role[m] - mx); s += ee[m]; }
    for (int m = 0; m < 7; ++m) sRole[m] = ee[m] / s;
  }
  sW1[t] = W1[t];
  sW2[t] = W2[t];
  if (t < 32) sB1[t] = b1[t];

  const int eloc = t >> 1;
  const int half = t & 1;
  const int el = blockIdx.x * 128 + eloc;
  const int ec = (el < B) ? el : (B - 1);   // clamped for loads (no early return)

  // ---- load + normalize my rows (even: 0-3, odd: 4-6), write LDS ----
  {
    const float* px = colony + (size_t)ec * 56;
#pragma unroll
    for (int nn = 0; nn < 4; ++nn) {
      int n = half * 4 + nn;
      if (n < 7) {
        float4 v0 = *(const float4*)(px + n * 8);
        float4 v1 = *(const float4*)(px + n * 8 + 4);
        float row[8] = { v0.x, v0.y, v0.z, v0.w, v1.x, v1.y, v1.z, v1.w };
        float ss = 0.f;
#pragma unroll
        for (int d = 0; d < 8; ++d) ss += row[d] * row[d];
        float inv = 1.0f / fmaxf(sqrtf(ss), 1e-12f);
#pragma unroll
        for (int d = 0; d < 8; ++d) x_lds[(n * 8 + d) * 128 + eloc] = row[d] * inv;
      }
    }
  }
  __syncthreads();   // x rows + staged weights visible to all

#define LDX(n, j) x_lds[(((n) << 3) + (j)) * 128 + eloc]

  // ---- xm: redundant, exact sequential order n=0..6 ----
  float xm[8];
#pragma unroll
  for (int d = 0; d < 8; ++d) xm[d] = 0.f;
#pragma unroll
  for (int n = 0; n < 7; ++n) {
#pragma unroll
    for (int d = 0; d < 8; ++d) xm[d] += LDX(n, d);
  }
#pragma unroll
  for (int d = 0; d < 8; ++d) xm[d] *= (1.0f / 7.0f);

  // ---- collapsed q.k scores (redundant) ----
  float w8[8];
#pragma unroll
  for (int j = 0; j < 8; ++j) {
    float a = 0.f;
#pragma unroll
    for (int i = 0; i < 8; ++i) a += xm[i] * sM8[i * 8 + j];
    w8[j] = a + sU[j];
  }
  float base = sCc[0];
#pragma unroll
  for (int i = 0; i < 8; ++i) base += sV[i] * xm[i];
  float sc[7];
#pragma unroll
  for (int n = 0; n < 7; ++n) {
    float a = base;
#pragma unroll
    for (int j = 0; j < 8; ++j) a += w8[j] * LDX(n, j);
    sc[n] = a * INV_SQRT32;
  }
  float sc2[7];
#pragma unroll
  for (int m = 0; m < 7; ++m) {
    float a = 0.f;
#pragma unroll
    for (int n = 0; n < 7; ++n) a += sc[n] * sComm[n * 7 + m];
    sc2[m] = a + sRole[m];
  }

  // ---- MHA split by head: even lanes h=0,1; odd lanes h=2,3 (uniform) ----
  float mhs_p[7];
#pragma unroll
  for (int m = 0; m < 7; ++m) mhs_p[m] = 0.f;
#pragma unroll
  for (int hh = 0; hh < 2; ++hh) {
    int h = half * 2 + hh;
    float Kh[7][2], Qh[7][2];
#pragma unroll
    for (int m = 0; m < 7; ++m) {
      float row[8];
#pragma unroll
      for (int j = 0; j < 8; ++j) row[j] = LDX(m, j);
      float k0 = sBk3[2 * h], k1 = sBk3[2 * h + 1];
      float q0 = sBq3[2 * h], q1 = sBq3[2 * h + 1];
#pragma unroll
      for (int j = 0; j < 8; ++j) {
        k0 += row[j] * sWk3[(2 * h) * 8 + j];
        k1 += row[j] * sWk3[(2 * h + 1) * 8 + j];
        q0 += row[j] * sWq3[(2 * h) * 8 + j];
        q1 += row[j] * sWq3[(2 * h + 1) * 8 + j];
      }
      Kh[m][0] = k0; Kh[m][1] = k1;
      Qh[m][0] = q0; Qh[m][1] = q1;
    }
#pragma unroll
    for (int n = 0; n < 7; ++n) {
      float ex[7], mx = -1e30f;
#pragma unroll
      for (int m = 0; m < 7; ++m) {
        float a = Qh[n][0] * Kh[m][0] + Qh[n][1] * Kh[m][1];
        ex[m] = a * INV_SQRT2;
        mx = fmaxf(mx, ex[m]);
      }
      float s = 0.f;
#pragma unroll
      for (int m = 0; m < 7; ++m) { ex[m] = __expf(ex[m] - mx); s += ex[m]; }
      float inv = 1.0f / s;
#pragma unroll
      for (int m = 0; m < 7; ++m) mhs_p[m] += ex[m] * inv;
    }
  }
  float mhs[7];
#pragma unroll
  for (int m = 0; m < 7; ++m) mhs[m] = pair_sum(mhs_p[m], half);

  // ---- combine scores, softmax, confidence re-norm (redundant) ----
  float scf[7], mx2 = -1e30f;
#pragma unroll
  for (int m = 0; m < 7; ++m) {
    scf[m] = 0.7f * sc2[m] + 0.3f * ((mhs[m] * 0.25f) * (1.0f / 7.0f));
    mx2 = fmaxf(mx2, scf[m]);
  }
  float ew[7], s2 = 0.f;
#pragma unroll
  for (int m = 0; m < 7; ++m) { ew[m] = __expf(scf[m] - mx2); s2 += ew[m]; }
  float sinv = 1.0f / s2;
  float w[7], ws = 0.f;
  const float* pc = conf + (size_t)ec * 7;
#pragma unroll
  for (int m = 0; m < 7; ++m) { w[m] = (ew[m] * sinv) * pc[m]; ws += w[m]; }
  float dinv = 1.0f / fmaxf(ws, 1e-8f);
#pragma unroll
  for (int m = 0; m < 7; ++m) w[m] = w[m] * dinv;

  // stage weights (even lane of each pair); copied out coalesced at the end
  if (!half) {
#pragma unroll
    for (int m = 0; m < 7; ++m) wlds[eloc * 7 + m] = w[m];
  }

  // ---- combined = Wv (sum_n w_n x_n) + bv (redundant, exact order) ----
  float xc[8];
#pragma unroll
  for (int d = 0; d < 8; ++d) xc[d] = 0.f;
#pragma unroll
  for (int n = 0; n < 7; ++n) {
#pragma unroll
    for (int d = 0; d < 8; ++d) xc[d] += w[n] * LDX(n, d);
  }
  float comb[8];
#pragma unroll
  for (int i = 0; i < 8; ++i) {
    float a = sBv[i];
#pragma unroll
    for (int j = 0; j < 8; ++j) a += sWv[i * 8 + j] * xc[j];
    comb[i] = a;
  }

  // ---- MLP split: even lanes i=0..15 (seeded with b2), odd i=16..31 ----
  float o8p[8];
#pragma unroll
  for (int k = 0; k < 8; ++k) o8p[k] = half ? 0.f : sB2[k];
#pragma unroll
  for (int ii = 0; ii < 16; ++ii) {
    int i = half * 16 + ii;
    float a = sB1[i];
#pragma unroll
    for (int j = 0; j < 8; ++j) a += sW1[i * 8 + j] * comb[j];
    float g = 0.5f * a * (1.f + erff(a * INV_SQRT2));
#pragma unroll
    for (int k = 0; k < 8; ++k) o8p[k] += sW2[k * 32 + i] * g;
  }
  float o8[8];
#pragma unroll
  for (int k = 0; k < 8; ++k) o8[k] = pair_sum(o8p[k], half);

  // ---- refined = norm(combined + sigmoid(gate)*h) (redundant) ----
  float gsig = sGate[0];
  float pre[8], ss2 = 0.f;
#pragma unroll
  for (int d = 0; d < 8; ++d) { pre[d] = comb[d] + gsig * o8[d]; ss2 += pre[d] * pre[d]; }
  float ninv = 1.0f / fmaxf(sqrtf(ss2), 1e-12f);
  float r[8];
#pragma unroll
  for (int d = 0; d < 8; ++d) r[d] = pre[d] * ninv;

  float* outq = out;
  float* outi = out + (size_t)B * 8;
  float* outw = out + (size_t)B * 9;

  // ---- nearest E8: even lane computes y0=nearest_d8(r), odd y1 (uniform) ----
  {
    float xs[8], y[8];
#pragma unroll
    for (int d = 0; d < 8; ++d) xs[d] = half ? (r[d] - 0.5f) : r[d];
    nearest_d8(xs, y);
#pragma unroll
    for (int d = 0; d < 8; ++d) y[d] = half ? (y[d] + 0.5f) : y[d];
    float dow = 0.f;
#pragma unroll
    for (int d = 0; d < 8; ++d) { float dd = r[d] - y[d]; dow += dd * dd; }
    float doth = __shfl_xor(dow, 1, 64);
    float dd0 = half ? doth : dow;
    float dd1 = half ? dow : doth;
    bool use0 = (dd0 <= dd1);
    bool mine_wins = (use0 == (half == 0));
    if (mine_wins && el < B) {
      float q0v[8];
#pragma unroll
      for (int d = 0; d < 8; ++d) q0v[d] = r[d] + (y[d] - r[d]);
      *(float4*)(outq + (size_t)el * 8)     = make_float4(q0v[0], q0v[1], q0v[2], q0v[3]);
      *(float4*)(outq + (size_t)el * 8 + 4) = make_float4(q0v[4], q0v[5], q0v[6], q0v[7]);
    }
  }

  // ---- argmin over 240 E8 roots ----
  // integer roots split by sign-pair: even lane s4={0,1}, odd s4={2,3} (uniform);
  // indices ascending within each lane => strict < keeps first occurrence.
  float ssum = 0.f;
#pragma unroll
  for (int d = 0; d < 8; ++d) ssum += r[d] * r[d];
  float bestSq = 1e30f;
  int bestIdx = 0;
  {
    int idx = 0;
#pragma unroll
    for (int i = 0; i < 8; ++i) {
#pragma unroll
      for (int j = i + 1; j < 8; ++j) {
        float a = r[i] + r[j];       // s4: 0=a, 1=b, 2=-b, 3=-a
        float bb = r[i] - r[j];
        float c0 = half ? -bb : a;
        float c1 = half ? -a : bb;
        float sq0 = fmaf(-2.f, c0, ssum) + 2.f;
        if (sq0 < bestSq) { bestSq = sq0; bestIdx = idx + 2 * half; }
        float sq1 = fmaf(-2.f, c1, ssum) + 2.f;
        if (sq1 < bestSq) { bestSq = sq1; bestIdx = idx + 2 * half + 1; }
        idx += 4;
      }
    }
  }
  // half-integer roots: both lanes run all 128 (identical r -> identical results;
  // keeps table indices compile-time, avoiding scratch).
  {
    float hr[8];
#pragma unroll
    for (int d = 0; d < 8; ++d) hr[d] = 0.5f * r[d];
    float sumhr = ((hr[0] + hr[1]) + (hr[2] + hr[3])) + ((hr[4] + hr[5]) + (hr[6] + hr[7]));
    float Thi[16], Tlo[16];
#pragma unroll
    for (int m = 0; m < 16; ++m) {
      float s1 = 0.f, sB_ = 0.f;
      if (m & 8) { s1 += hr[0]; sB_ += hr[4]; }
      if (m & 4) { s1 += hr[1]; sB_ += hr[5]; }
      if (m & 2) { s1 += hr[2]; sB_ += hr[6]; }
      if (m & 1) { s1 += hr[3]; sB_ += hr[7]; }
      Thi[m] = s1; Tlo[m] = sB_;
    }
#pragma unroll
    for (int k = 0; k < 128; ++k) {
      const int c = (k << 1) | (__popc(k) & 1);
      float T = Thi[c >> 4] + Tlo[c & 15];
      float dot = sumhr - 2.f * T;
      float sq = fmaf(-2.f, dot, ssum) + 2.f;
      if (sq < bestSq) { bestSq = sq; bestIdx = 112 + k; }
    }
  }
  // cross-lane combine, exact first-index-wins: lexicographic (sq, idx) min
  {
    float oSq = __shfl_xor(bestSq, 1, 64);
    int oIdx = __shfl_xor(bestIdx, 1, 64);
    if (oSq < bestSq || (oSq == bestSq && oIdx < bestIdx)) { bestSq = oSq; bestIdx = oIdx; }
    if (!half && el < B) outi[el] = (float)bestIdx;
  }

  // ---- coalesced weights store ----
  __syncthreads();
  {
    const size_t wbase = (size_t)blockIdx.x * 896;
    const size_t wtot = (size_t)B * 7;
    float* dst = outw + wbase;
#pragma unroll
    for (int k = 0; k < 4; ++k) {
      int idx = k * 256 + t;
      if (idx < 896 && wbase + idx < wtot) dst[idx] = wlds[idx];
    }
  }
#undef LDX
}

extern "C" void kernel_launch(void* const* d_in, const int* in_sizes, int n_in,
                              void* d_out, int out_size, void* d_ws, size_t ws_size,
                              hipStream_t stream) {
  const float* colony = (const float*)d_in[0];
  const float* conf   = (const float*)d_in[1];
  const float* Wq     = (const float*)d_in[2];
  const float* bq     = (const float*)d_in[3];
  const float* Wk     = (const float*)d_in[4];
  const float* bk     = (const float*)d_in[5];
  const float* Wv     = (const float*)d_in[6];
  const float* bv     = (const float*)d_in[7];
  const float* comm   = (const float*)d_in[8];
  const float* role   = (const float*)d_in[9];
  const float* mhaw   = (const float*)d_in[10];
  const float* mhab   = (const float*)d_in[11];
  const float* W1     = (const float*)d_in[12];
  const float* b1     = (const float*)d_in[13];
  const float* W2     = (const float*)d_in[14];
  const float* b2     = (const float*)d_in[15];
  const float* gate   = (const float*)d_in[16];

  int B = in_sizes[0] / 56;
  dim3 grid((B + 127) / 128), block(256);
  hipLaunchKernelGGL(e8_kernel, grid, block, 0, stream,
                     colony, conf, Wq, bq, Wk, bk, Wv, bv, comm, role,
                     mhaw, mhab, W1, b1, W2, b2, gate, (float*)d_out, B);
}

// Round 9
// 147.998 us; speedup vs baseline: 5.3287x; 1.1129x over previous
//
#include <hip/hip_runtime.h>
#include <math.h>

#define INV_SQRT2 0.70710678118654752f
#define INV_SQRT32 0.17677669529663689f

// 4 threads per element (quad q = t&3). 256 thr/block -> 64 elements/block.
// x lives in LDS [feature][elem] with stride 65 (bank = (f+eloc)%32: quad
// writes hit distinct banks; reads are same-address broadcasts). Work split
// with UNIFORM control flow: 1 MHA head/lane, 8 MLP neurons/lane, 2 x-rows/
// lane, argmin quartered. Independent dots (w8/sc/sc2/xc/comb) computed whole
// by one owner lane (bit-exact sequential) and broadcast via __shfl(.,.,4).
// Order-sensitive sums (xm, mhs, o8) use canonical butterfly ((p0+p1)+(p2+p3))
// so all 4 lanes hold identical bits. No occupancy attributes (rounds 2-6:
// every hint => allocator over-squeeze => catastrophic scratch spill).
__device__ __forceinline__ void nearest_d8(const float* xx, float* y) {
  float f[8], err[8];
#pragma unroll
  for (int d = 0; d < 8; ++d) { f[d] = rintf(xx[d]); err[d] = xx[d] - f[d]; }
  int idx = 0; float best = -1.0f;
#pragma unroll
  for (int d = 0; d < 8; ++d) { float a = fabsf(err[d]); if (a > best) { best = a; idx = d; } }
  float fs = 0.f;
#pragma unroll
  for (int d = 0; d < 8; ++d) fs += f[d];
  bool ok = ((((int)fs) & 1) == 0);
#pragma unroll
  for (int d = 0; d < 8; ++d) {
    float g = f[d] + ((d == idx) ? ((err[d] >= 0.f) ? 1.f : -1.f) : 0.f);
    y[d] = ok ? f[d] : g;
  }
}

// canonical quad sum ((p0+p1)+(p2+p3)); all 4 lanes end with identical bits
__device__ __forceinline__ float qsum(float v, int q) {
  float o1 = __shfl_xor(v, 1, 64);
  float s1 = (q & 1) ? (o1 + v) : (v + o1);
  float o2 = __shfl_xor(s1, 2, 64);
  return (q & 2) ? (o2 + s1) : (s1 + o2);
}

extern "C" __global__ void __launch_bounds__(256)
e8_kernel(const float* __restrict__ colony, const float* __restrict__ conf,
          const float* __restrict__ Wq, const float* __restrict__ bq,
          const float* __restrict__ Wk, const float* __restrict__ bk,
          const float* __restrict__ Wv, const float* __restrict__ bv,
          const float* __restrict__ comm, const float* __restrict__ role,
          const float* __restrict__ mha_w, const float* __restrict__ mha_b,
          const float* __restrict__ W1, const float* __restrict__ b1,
          const float* __restrict__ W2, const float* __restrict__ b2,
          const float* __restrict__ gate, float* __restrict__ out, int B)
{
  __shared__ float x_lds[56 * 65];    // [feature f][elem eloc], stride 65
  __shared__ float wlds[7 * 64];      // block's outw image for coalesced store
  __shared__ float sM8[64], sU[8], sV[8], sCc[1];
  __shared__ float sComm[49], sRole[7];
  __shared__ float sWq3[64], sWk3[64], sBq3[8], sBk3[8];
  __shared__ float sWv[64], sBv[8];
  __shared__ float sW1[256], sB1[32], sW2[256], sB2[8];
  __shared__ float sGate[1];

  const int t = threadIdx.x;
  if (t < 64) {
    int i = t >> 3, j = t & 7;
    float a = 0.f;
    for (int h = 0; h < 32; ++h) a += Wq[h * 8 + i] * Wk[h * 8 + j];
    sM8[t] = a;
    sWq3[t] = mha_w[t];
    sWk3[t] = mha_w[64 + t];
    sWv[t] = Wv[t];
  } else if (t < 72) {
    int j = t - 64;
    float a = 0.f, bb = 0.f;
    for (int h = 0; h < 32; ++h) { a += bq[h] * Wk[h * 8 + j]; bb += bk[h] * Wq[h * 8 + j]; }
    sU[j] = a; sV[j] = bb;
    sBq3[j] = mha_b[j]; sBk3[j] = mha_b[8 + j]; sBv[j] = bv[j]; sB2[j] = b2[j];
  } else if (t == 72) {
    float c = 0.f;
    for (int h = 0; h < 32; ++h) c += bq[h] * bk[h];
    sCc[0] = c;
    sGate[0] = 1.f / (1.f + expf(-gate[0]));
  } else if (t >= 80 && t < 87) {
    int n = t - 80;
    float mx = -1e30f;
    for (int m = 0; m < 7; ++m) mx = fmaxf(mx, comm[n * 7 + m]);
    float ee[7], s = 0.f;
    for (int m = 0; m < 7; ++m) { ee[m] = expf(comm[n * 7 + m] - mx); s += ee[m]; }
    for (int m = 0; m < 7; ++m) sComm[n * 7 + m] = ee[m] / s;
  } else if (t == 87) {
    float mx = -1e30f;
    for (int m = 0; m < 7; ++m) mx = fmaxf(mx, role[m]);
    float ee[7], s = 0.f;
    for (int m = 0; m < 7; ++m) { ee[m] = expf(role[m] - mx); s += ee[m]; }
    for (int m = 0; m < 7; ++m) sRole[m] = ee[m] / s;
  }
  sW1[t] = W1[t];
  sW2[t] = W2[t];
  if (t < 32) sB1[t] = b1[t];

  const int q    = t & 3;
  const int eloc = t >> 2;
  const int el   = blockIdx.x * 64 + eloc;
  const int ec   = (el < B) ? el : (B - 1);   // clamped loads, no early return
  const bool q3  = (q < 3);
  const int n1 = q;
  const int n2 = q3 ? q + 4 : 3;   // lane3 harmlessly redoes row 3

#define LDX(n, j) x_lds[(((n) << 3) + (j)) * 65 + eloc]

  // ---- load + normalize my 2 rows -> LDS ----
  {
    const float* px = colony + (size_t)ec * 56;
#pragma unroll
    for (int rr = 0; rr < 2; ++rr) {
      int n = rr ? n2 : n1;
      float4 v0 = *(const float4*)(px + n * 8);
      float4 v1 = *(const float4*)(px + n * 8 + 4);
      float row[8] = { v0.x, v0.y, v0.z, v0.w, v1.x, v1.y, v1.z, v1.w };
      float ss = 0.f;
#pragma unroll
      for (int d = 0; d < 8; ++d) ss += row[d] * row[d];
      float inv = 1.0f / fmaxf(sqrtf(ss), 1e-12f);
#pragma unroll
      for (int d = 0; d < 8; ++d) x_lds[((n << 3) + d) * 65 + eloc] = row[d] * inv;
    }
  }
  __syncthreads();

  // ---- xm via canonical quad sum ----
  float xm[8];
#pragma unroll
  for (int d = 0; d < 8; ++d) {
    float a = LDX(n1, d);
    float bpart = LDX(n2, d);
    float p = q3 ? (a + bpart) : a;
    xm[d] = qsum(p, q) * (1.0f / 7.0f);
  }

  // ---- w8 split: lane q owns j=q and j=q+4 (exact sequential dots) ----
  float w8[8];
  {
    float a0 = 0.f, a1 = 0.f;
#pragma unroll
    for (int i = 0; i < 8; ++i) {
      a0 += xm[i] * sM8[i * 8 + q];
      a1 += xm[i] * sM8[i * 8 + q + 4];
    }
    a0 += sU[q]; a1 += sU[q + 4];
#pragma unroll
    for (int j = 0; j < 4; ++j) w8[j] = __shfl(a0, j, 4);
#pragma unroll
    for (int j = 4; j < 8; ++j) w8[j] = __shfl(a1, j - 4, 4);
  }
  float base = sCc[0];
#pragma unroll
  for (int i = 0; i < 8; ++i) base += sV[i] * xm[i];

  // ---- sc split: lane q owns n1, n2 ----
  float sc[7];
  {
    float sA = base, sB_ = base;
#pragma unroll
    for (int j = 0; j < 8; ++j) {
      sA  += w8[j] * LDX(n1, j);
      sB_ += w8[j] * LDX(n2, j);
    }
    sA *= INV_SQRT32; sB_ *= INV_SQRT32;
#pragma unroll
    for (int n = 0; n < 4; ++n) sc[n] = __shfl(sA, n, 4);
#pragma unroll
    for (int n = 4; n < 7; ++n) sc[n] = __shfl(sB_, n - 4, 4);
  }

  // ---- sc2 split: lane q owns m=q and m=n2 ----
  float sc2[7];
  {
    float a0 = 0.f, a1 = 0.f;
#pragma unroll
    for (int n = 0; n < 7; ++n) {
      a0 += sc[n] * sComm[n * 7 + q];
      a1 += sc[n] * sComm[n * 7 + n2];
    }
    a0 += sRole[q]; a1 += sRole[n2];
#pragma unroll
    for (int m = 0; m < 4; ++m) sc2[m] = __shfl(a0, m, 4);
#pragma unroll
    for (int m = 4; m < 7; ++m) sc2[m] = __shfl(a1, m - 4, 4);
  }

  // ---- MHA: 1 head per lane (h = q) ----
  float mhs[7];
  {
    float Kh[7][2], Qh[7][2];
#pragma unroll
    for (int m = 0; m < 7; ++m) {
      float row[8];
#pragma unroll
      for (int j = 0; j < 8; ++j) row[j] = LDX(m, j);
      float k0 = sBk3[2 * q], k1 = sBk3[2 * q + 1];
      float q0 = sBq3[2 * q], q1 = sBq3[2 * q + 1];
#pragma unroll
      for (int j = 0; j < 8; ++j) {
        k0 += row[j] * sWk3[(2 * q) * 8 + j];
        k1 += row[j] * sWk3[(2 * q + 1) * 8 + j];
        q0 += row[j] * sWq3[(2 * q) * 8 + j];
        q1 += row[j] * sWq3[(2 * q + 1) * 8 + j];
      }
      Kh[m][0] = k0; Kh[m][1] = k1;
      Qh[m][0] = q0; Qh[m][1] = q1;
    }
    float mp[7];
#pragma unroll
    for (int m = 0; m < 7; ++m) mp[m] = 0.f;
#pragma unroll
    for (int n = 0; n < 7; ++n) {
      float ex[7], mx = -1e30f;
#pragma unroll
      for (int m = 0; m < 7; ++m) {
        float a = Qh[n][0] * Kh[m][0] + Qh[n][1] * Kh[m][1];
        ex[m] = a * INV_SQRT2;
        mx = fmaxf(mx, ex[m]);
      }
      float s = 0.f;
#pragma unroll
      for (int m = 0; m < 7; ++m) { ex[m] = __expf(ex[m] - mx); s += ex[m]; }
      float inv = 1.0f / s;
#pragma unroll
      for (int m = 0; m < 7; ++m) mp[m] += ex[m] * inv;
    }
#pragma unroll
    for (int m = 0; m < 7; ++m) mhs[m] = qsum(mp[m], q);
  }

  // ---- combine scores, softmax, confidence re-norm (redundant, identical) ----
  float scf[7], mx2 = -1e30f;
#pragma unroll
  for (int m = 0; m < 7; ++m) {
    scf[m] = 0.7f * sc2[m] + 0.3f * ((mhs[m] * 0.25f) * (1.0f / 7.0f));
    mx2 = fmaxf(mx2, scf[m]);
  }
  float ew[7], s2 = 0.f;
#pragma unroll
  for (int m = 0; m < 7; ++m) { ew[m] = __expf(scf[m] - mx2); s2 += ew[m]; }
  float sinv = 1.0f / s2;
  float w[7], ws = 0.f;
  const float* pc = conf + (size_t)ec * 7;
#pragma unroll
  for (int m = 0; m < 7; ++m) { w[m] = (ew[m] * sinv) * pc[m]; ws += w[m]; }
  float dinv = 1.0f / fmaxf(ws, 1e-8f);
#pragma unroll
  for (int m = 0; m < 7; ++m) w[m] = w[m] * dinv;

  if (q == 0) {
#pragma unroll
    for (int m = 0; m < 7; ++m) wlds[eloc * 7 + m] = w[m];
  }

  // ---- xc split by dim: lane q owns d=q and d=q+4 (exact n-order chains) ----
  float xc[8];
  {
    float a0 = 0.f, a1 = 0.f;
#pragma unroll
    for (int n = 0; n < 7; ++n) {
      a0 += w[n] * LDX(n, q);
      a1 += w[n] * LDX(n, q + 4);
    }
#pragma unroll
    for (int d = 0; d < 4; ++d) xc[d] = __shfl(a0, d, 4);
#pragma unroll
    for (int d = 4; d < 8; ++d) xc[d] = __shfl(a1, d - 4, 4);
  }

  // ---- comb split: lane q owns i=q and i=q+4 ----
  float comb[8];
  {
    float a0 = sBv[q], a1 = sBv[q + 4];
#pragma unroll
    for (int j = 0; j < 8; ++j) {
      a0 += sWv[q * 8 + j] * xc[j];
      a1 += sWv[(q + 4) * 8 + j] * xc[j];
    }
#pragma unroll
    for (int i = 0; i < 4; ++i) comb[i] = __shfl(a0, i, 4);
#pragma unroll
    for (int i = 4; i < 8; ++i) comb[i] = __shfl(a1, i - 4, 4);
  }

  // ---- MLP: 8 neurons per lane (i = 8q..8q+7), canonical combine ----
  float o8[8];
  {
    float op[8];
#pragma unroll
    for (int k = 0; k < 8; ++k) op[k] = (q == 0) ? sB2[k] : 0.f;
#pragma unroll
    for (int ii = 0; ii < 8; ++ii) {
      int i = 8 * q + ii;
      float a = sB1[i];
#pragma unroll
      for (int j = 0; j < 8; ++j) a += sW1[i * 8 + j] * comb[j];
      float g = 0.5f * a * (1.f + erff(a * INV_SQRT2));
#pragma unroll
      for (int k = 0; k < 8; ++k) op[k] += sW2[k * 32 + i] * g;
    }
#pragma unroll
    for (int k = 0; k < 8; ++k) o8[k] = qsum(op[k], q);
  }

  // ---- refined = norm(combined + sigmoid(gate)*h) (redundant, identical) ----
  float gsig = sGate[0];
  float pre[8], ssq = 0.f;
#pragma unroll
  for (int d = 0; d < 8; ++d) { pre[d] = comb[d] + gsig * o8[d]; ssq += pre[d] * pre[d]; }
  float ninv = 1.0f / fmaxf(sqrtf(ssq), 1e-12f);
  float r[8];
#pragma unroll
  for (int d = 0; d < 8; ++d) r[d] = pre[d] * ninv;

  float* outq = out;
  float* outi = out + (size_t)B * 8;
  float* outw = out + (size_t)B * 9;

  // ---- nearest E8: lanes q<2 compute y0, q>=2 compute y1 ----
  {
    const int h2 = q >> 1;
    float xs[8], y[8];
#pragma unroll
    for (int d = 0; d < 8; ++d) xs[d] = h2 ? (r[d] - 0.5f) : r[d];
    nearest_d8(xs, y);
#pragma unroll
    for (int d = 0; d < 8; ++d) y[d] = h2 ? (y[d] + 0.5f) : y[d];
    float dow = 0.f;
#pragma unroll
    for (int d = 0; d < 8; ++d) { float dd = r[d] - y[d]; dow += dd * dd; }
    float doth = __shfl_xor(dow, 2, 64);
    float dd0 = h2 ? doth : dow;
    float dd1 = h2 ? dow : doth;
    bool use0 = (dd0 <= dd1);
    bool mine_wins = (use0 == (h2 == 0));
    if (mine_wins && ((q & 1) == 0) && el < B) {
      float qv[8];
#pragma unroll
      for (int d = 0; d < 8; ++d) qv[d] = r[d] + (y[d] - r[d]);
      *(float4*)(outq + (size_t)el * 8)     = make_float4(qv[0], qv[1], qv[2], qv[3]);
      *(float4*)(outq + (size_t)el * 8 + 4) = make_float4(qv[4], qv[5], qv[6], qv[7]);
    }
  }

  // ---- argmin over 240 E8 roots, quartered ----
  float ssum = 0.f;
#pragma unroll
  for (int d = 0; d < 8; ++d) ssum += r[d] * r[d];
  float bestSq = 1e30f;
  int bestIdx = 0;
  // integer roots: lane q takes sign-combo s4=q of every (i,j) pair
  {
    int idx = 0;
#pragma unroll
    for (int i = 0; i < 8; ++i) {
#pragma unroll
      for (int j = i + 1; j < 8; ++j) {
        float a = r[i] + r[j];       // s4: 0=a, 1=b, 2=-b, 3=-a
        float bb = r[i] - r[j];
        float t1 = (q & 2) ? -bb : a;
        float t2 = (q & 2) ? -a  : bb;
        float c  = (q & 1) ? t2 : t1;
        float sq = fmaf(-2.f, c, ssum) + 2.f;
        if (sq < bestSq) { bestSq = sq; bestIdx = idx; }
        idx += 4;
      }
    }
    bestIdx += q;   // absolute index (a hit always occurred)
  }
  // half-integer roots: lane q takes k = 32q..32q+31. Per-lane tables hold the
  // lane's slice of Thi/Tlo with build order preserved add-by-add, so every T
  // matches the (passing) full-table chain bit-for-bit.
  {
    float hr[8];
#pragma unroll
    for (int d = 0; d < 8; ++d) hr[d] = 0.5f * r[d];
    float sumhr = ((hr[0] + hr[1]) + (hr[2] + hr[3])) + ((hr[4] + hr[5]) + (hr[6] + hr[7]));
    // hi-table slice: m = 4q+i. bits: hr[0] iff q&2 (first), hr[1] iff q&1,
    // then hr[2] (i&2), hr[3] (i&1) in order.
    float tb0 = (q & 2) ? hr[0] : 0.f;
    float tb  = (q & 1) ? (tb0 + hr[1]) : tb0;
    float Th[4];
    Th[0] = tb;
    Th[1] = tb + hr[3];
    Th[2] = tb + hr[2];
    Th[3] = (tb + hr[2]) + hr[3];
    // lo-table base over hr[4],hr[5],hr[6] (sequential build from 0)
    float TloB[8];
    TloB[0] = 0.f;
    TloB[4] = 0.f + hr[4];
    TloB[2] = 0.f + hr[5];
    TloB[6] = hr[4] + hr[5];
    TloB[1] = 0.f + hr[6];
    TloB[5] = hr[4] + hr[6];
    TloB[3] = hr[5] + hr[6];
    TloB[7] = (hr[4] + hr[5]) + hr[6];
    const int pq = ((q >> 1) ^ q) & 1;          // popc(q)&1
    const float hpE = pq ? hr[7] : 0.f;         // parity(kk)==0 -> add iff pq
    const float hpO = pq ? 0.f : hr[7];         // parity(kk)==1 -> add iff !pq
    const int hbase = 112 + (q << 5);
#pragma unroll
    for (int kk = 0; kk < 32; ++kk) {
      float tl = TloB[kk & 7] + ((__popc(kk) & 1) ? hpO : hpE);
      float T = Th[kk >> 3] + tl;
      float dot = sumhr - 2.f * T;
      float sq = fmaf(-2.f, dot, ssum) + 2.f;
      if (sq < bestSq) { bestSq = sq; bestIdx = hbase + kk; }
    }
  }
  // cross-lane combine: lexicographic (sq, idx) min == global first-min
  {
#pragma unroll
    for (int mlev = 1; mlev <= 2; mlev <<= 1) {
      float oSq = __shfl_xor(bestSq, mlev, 64);
      int   oIx = __shfl_xor(bestIdx, mlev, 64);
      if (oSq < bestSq || (oSq == bestSq && oIx < bestIdx)) { bestSq = oSq; bestIdx = oIx; }
    }
    if (q == 0 && el < B) outi[el] = (float)bestIdx;
  }

  // ---- coalesced weights store ----
  __syncthreads();
  {
    const size_t wbase = (size_t)blockIdx.x * 448;
    const size_t wtot = (size_t)B * 7;
#pragma unroll
    for (int k2 = 0; k2 < 2; ++k2) {
      int idx2 = k2 * 256 + t;
      if (idx2 < 448 && wbase + idx2 < wtot) outw[wbase + idx2] = wlds[idx2];
    }
  }
#undef LDX
}

extern "C" void kernel_launch(void* const* d_in, const int* in_sizes, int n_in,
                              void* d_out, int out_size, void* d_ws, size_t ws_size,
                              hipStream_t stream) {
  const float* colony = (const float*)d_in[0];
  const float* conf   = (const float*)d_in[1];
  const float* Wq     = (const float*)d_in[2];
  const float* bq     = (const float*)d_in[3];
  const float* Wk     = (const float*)d_in[4];
  const float* bk     = (const float*)d_in[5];
  const float* Wv     = (const float*)d_in[6];
  const float* bv     = (const float*)d_in[7];
  const float* comm   = (const float*)d_in[8];
  const float* role   = (const float*)d_in[9];
  const float* mhaw   = (const float*)d_in[10];
  const float* mhab   = (const float*)d_in[11];
  const float* W1     = (const float*)d_in[12];
  const float* b1     = (const float*)d_in[13];
  const float* W2     = (const float*)d_in[14];
  const float* b2     = (const float*)d_in[15];
  const float* gate   = (const float*)d_in[16];

  int B = in_sizes[0] / 56;
  dim3 grid((B + 63) / 64), block(256);
  hipLaunchKernelGGL(e8_kernel, grid, block, 0, stream,
                     colony, conf, Wq, bq, Wk, bk, Wv, bv, comm, role,
                     mhaw, mhab, W1, b1, W2, b2, gate, (float*)d_out, B);
}